// Round 16
// baseline (797.321 us; speedup 1.0000x reference)
//
#include <hip/hip_runtime.h>
#include <hip/hip_bf16.h>
#include <stdint.h>

#define S_LEN 2048
#define E_DIM 128
#define KT 32
#define KTM 64   // mono fallback tile

// ws: [0,8Mi) KH | [8Mi,16Mi) KL | [16Mi,24Mi) VT | [24Mi,..) split-K partials
#define ARR_BYTES    (8u * 1024 * 1024)         // 16*2048*128 bf16
#define PART2_FLOATS 16640                      // per block: m[128],den[128],O[128][128]
#define TIER_B       ((size_t)3u * ARR_BYTES)
#define TIER_A2      (TIER_B + (size_t)512 * PART2_FLOATS * 4)   // 59.2MB
#define TIER_A4      (TIER_B + (size_t)1024 * PART2_FLOATS * 4)  // 93.3MB

typedef __attribute__((ext_vector_type(4))) float f32x4;
typedef __attribute__((ext_vector_type(4))) short s16x4;
typedef __attribute__((ext_vector_type(8))) short bf16x8;

__device__ __forceinline__ short f2bf(float f) {
    uint32_t u = __builtin_bit_cast(uint32_t, f);
    u += 0x7FFFu + ((u >> 16) & 1u);
    return (short)(u >> 16);
}
__device__ __forceinline__ float bf2f(short h) {
    uint32_t u = ((uint32_t)(uint16_t)h) << 16;
    return __builtin_bit_cast(float, u);
}
__device__ __forceinline__ uint32_t cvtpk_bf16(float lo, float hi) {
    uint32_t d;
    asm volatile("v_cvt_pk_bf16_f32 %0, %1, %2" : "=v"(d) : "v"(lo), "v"(hi));
    return d;
}

// Threefry-2x32, rotl via v_alignbit (KAT-certified on gfx950 r4/r5)
__device__ __forceinline__ void threefry_g(uint32_t k0, uint32_t k1,
                                           uint32_t c0, uint32_t c1,
                                           uint32_t& y0, uint32_t& y1) {
    uint32_t ks2 = k0 ^ k1 ^ 0x1BD11BDAu;
    uint32_t x0 = c0 + k0, x1 = c1 + k1;
#define TF_R(rr) { x0 += x1; x1 = __builtin_amdgcn_alignbit(x1, x1, 32u - rr); x1 ^= x0; }
    TF_R(13) TF_R(15) TF_R(26) TF_R(6)
    x0 += k1;  x1 += ks2 + 1u;
    TF_R(17) TF_R(29) TF_R(16) TF_R(24)
    x0 += ks2; x1 += k0 + 2u;
    TF_R(13) TF_R(15) TF_R(26) TF_R(6)
    x0 += k0;  x1 += k1 + 3u;
    TF_R(17) TF_R(29) TF_R(16) TF_R(24)
    x0 += k1;  x1 += ks2 + 4u;
    TF_R(13) TF_R(15) TF_R(26) TF_R(6)
    x0 += ks2; x1 += k0 + 5u;
#undef TF_R
    y0 = x0; y1 = x1;
}

// JAX partitionable threefry, x64 off: ctr=(0,j), draw=y0^y1 (certified r4-r15)
__device__ __forceinline__ bool keep_bit(uint32_t j) {
    uint32_t y0, y1;
    threefry_g(0u, 42u, 0u, j, y0, y1);
    return (y0 ^ y1) < 0xE6666600u;
}

// ============ kernel 0: one-time K/V convert (split bf16 + V transpose) ====
__global__ __launch_bounds__(256, 4)
void convert_kv(const float* __restrict__ Kg, const float* __restrict__ Vg,
                short* __restrict__ KH, short* __restrict__ KL,
                short* __restrict__ VT) {
    __shared__ short vs[64][130];
    const int blk = blockIdx.x;           // 512 = 16 b x 32 tiles
    const int b = blk >> 5, t = blk & 31;
    const size_t base = ((size_t)b * S_LEN + (size_t)t * 64) * E_DIM;
    const int e0 = (threadIdx.x & 31) * 4;
    const int rb = threadIdx.x >> 5;
    #pragma unroll
    for (int it = 0; it < 8; ++it) {
        int row = it * 8 + rb;
        f32x4 kv = *(const f32x4*)(Kg + base + row * E_DIM + e0);
        s16x4 h, lo;
        #pragma unroll
        for (int i = 0; i < 4; ++i) {
            short hh = f2bf(kv[i]);
            h[i]  = hh;
            lo[i] = f2bf(kv[i] - bf2f(hh));
        }
        *(s16x4*)(KH + base + row * E_DIM + e0) = h;
        *(s16x4*)(KL + base + row * E_DIM + e0) = lo;
        f32x4 vv = *(const f32x4*)(Vg + base + row * E_DIM + e0);
        #pragma unroll
        for (int i = 0; i < 4; ++i) vs[row][e0 + i] = f2bf(vv[i]);
    }
    __syncthreads();
    const int e = threadIdx.x >> 1;
    const int k2 = (threadIdx.x & 1) * 32;
    short* dst = VT + ((size_t)b * E_DIM + e) * S_LEN + t * 64 + k2;
    #pragma unroll
    for (int i = 0; i < 32; i += 4) {
        s16x4 v;
        #pragma unroll
        for (int q2 = 0; q2 < 4; ++q2) v[q2] = vs[k2 + i + q2][e];
        *(s16x4*)(dst + i) = v;
    }
}

// == kernel 1: QT=128 8-wave swapped attn, shfl P-redistribution (no plt) ===
template<int NSPLIT>
__global__ __launch_bounds__(512, 8)
void attn10(const float* __restrict__ Qg, const short* __restrict__ KH,
            const short* __restrict__ KL, const short* __restrict__ VT,
            float* __restrict__ outp) {
    constexpr int NT = (S_LEN / NSPLIT) / KT;
    __shared__ __attribute__((aligned(16))) short kh[KT * E_DIM];  // 8 KB swz
    __shared__ __attribute__((aligned(16))) short kl[KT * E_DIM];  // 8 KB
    __shared__ __attribute__((aligned(16))) short vt[E_DIM * 40];  // 10 KB
    __shared__ uint32_t mldsT[NT][128];   // NS=4: 8 KB

    const int tid = threadIdx.x;
    const int w   = tid >> 6;             // 0..7
    const int ln  = tid & 63;
    const int r   = ln & 15;
    const int g   = ln >> 4;
    const int nwg = 256 * NSPLIT;
    const int wg  = (blockIdx.x & 7) * (nwg >> 3) + (blockIdx.x >> 3);
    const int t   = wg / NSPLIT;          // 0..255
    const int s   = wg % NSPLIT;
    const int b   = t >> 4;
    const int q0  = (t & 15) << 7;        // 128-row Q tile
    const int k0g = s * (S_LEN / NSPLIT);
    const size_t boff = (size_t)b * S_LEN * E_DIM;

    // ---- Q fragments (B-operand of swapped QK^T), split bf16 in regs ----
    bf16x8 qh[4], ql[4];
    #pragma unroll
    for (int ec = 0; ec < 4; ++ec) {
        const float* src = Qg + boff + (size_t)(q0 + w * 16 + r) * E_DIM + ec * 32 + g * 8;
        f32x4 va = *(const f32x4*)(src);
        f32x4 vb2 = *(const f32x4*)(src + 4);
        #pragma unroll
        for (int i = 0; i < 4; ++i) {
            short hh = f2bf(va[i]);
            qh[ec][i] = hh;
            ql[ec][i] = f2bf(va[i] - bf2f(hh));
            short h2 = f2bf(vb2[i]);
            qh[ec][4 + i] = h2;
            ql[ec][4 + i] = f2bf(vb2[i] - bf2f(h2));
        }
    }

    // ---- mask prologue: wave w rows w*16..+15, transposed store ----
    {
        constexpr int segs = (S_LEN / NSPLIT) / 64;
        const uint32_t jb = (((uint32_t)b << 11) + (uint32_t)q0) * 2048u
                          + (uint32_t)k0g + (uint32_t)ln;
        for (int rr = 0; rr < 16; ++rr) {
            uint32_t jrow = jb + (uint32_t)(w * 16 + rr) * 2048u;
            #pragma unroll
            for (int seg = 0; seg < segs; ++seg) {
                uint64_t m = __ballot(keep_bit(jrow + (uint32_t)(seg * 64)));
                if (ln < 2) mldsT[seg * 2 + ln][w * 16 + rr] = (uint32_t)(m >> (ln * 32));
            }
        }
    }

    const short* KHb = KH + ((size_t)b * S_LEN + k0g) * E_DIM;
    const short* KLb = KL + ((size_t)b * S_LEN + k0g) * E_DIM;
    const short* VTb = VT + (size_t)b * E_DIM * S_LEN + k0g;

    // staging (T14): 512 threads stage one 32x128 K tile + 128x32 V^T tile
    bf16x8 skh, skl, svv;
    const int se0 = (tid & 15) * 8;
    const int srl = tid >> 4;             // k-row 0..31
    const int sve = tid >> 2;             // e 0..127
    const int svq = tid & 3;              // chunk 0..3
#define LOAD_TILE(ktt)                                                          \
    {                                                                           \
        skh = *(const bf16x8*)(KHb + (size_t)((ktt) * KT + srl) * E_DIM + se0); \
        skl = *(const bf16x8*)(KLb + (size_t)((ktt) * KT + srl) * E_DIM + se0); \
        svv = *(const bf16x8*)(VTb + (size_t)sve * S_LEN + (ktt) * KT + svq * 8); \
    }
    LOAD_TILE(0)

    f32x4 oacc[8];
    #pragma unroll
    for (int i = 0; i < 8; ++i) oacc[i] = f32x4{0.f, 0.f, 0.f, 0.f};
    float mrun = -1e30f, den = 0.f;

    for (int kt = 0; kt < NT; ++kt) {
        __syncthreads();   // prev tile's LDS readers done (covers mlds at kt=0)
        // ---- LDS writes of staged regs ----
        {
            int idx = (srl * E_DIM + se0) ^ ((srl & 7) << 3);
            *(bf16x8*)(kh + idx) = skh;
            *(bf16x8*)(kl + idx) = skl;
            const int swv = ((sve >> 3) & 1) << 1;
            *(bf16x8*)(vt + sve * 40 + ((svq ^ swv) << 3)) = svv;
        }
        __syncthreads();

        // ---- S^T = K Q^T: 3-MFMA split (certified r10 numerics) ----
        f32x4 sc[2];
        #pragma unroll
        for (int c = 0; c < 2; ++c) {
            f32x4 acc = f32x4{0.f, 0.f, 0.f, 0.f};
            int krow = c * 16 + r;
            int sw = (krow & 7) << 3;
            #pragma unroll
            for (int ec = 0; ec < 4; ++ec) {
                int idx = (krow * E_DIM + ec * 32 + g * 8) ^ sw;
                bf16x8 bh = *(const bf16x8*)(kh + idx);
                bf16x8 bl = *(const bf16x8*)(kl + idx);
                acc = __builtin_amdgcn_mfma_f32_16x16x32_bf16(bh, qh[ec], acc, 0, 0, 0);
                acc = __builtin_amdgcn_mfma_f32_16x16x32_bf16(bl, qh[ec], acc, 0, 0, 0);
                acc = __builtin_amdgcn_mfma_f32_16x16x32_bf16(bh, ql[ec], acc, 0, 0, 0);
            }
            sc[c] = acc;
        }

        // ---- softmax (per-lane scalar state, 2 shuffles per reduce) ----
        float pmax = fmaxf(fmaxf(fmaxf(sc[0][0], sc[0][1]), fmaxf(sc[0][2], sc[0][3])),
                           fmaxf(fmaxf(sc[1][0], sc[1][1]), fmaxf(sc[1][2], sc[1][3])));
        pmax = fmaxf(pmax, __shfl_xor(pmax, 16));
        pmax = fmaxf(pmax, __shfl_xor(pmax, 32));
        if (__any(pmax - mrun > 8.0f)) {       // defer-max
            float mnew = fmaxf(mrun, pmax);
            float scl = __expf(mrun - mnew);
            mrun = mnew;
            den *= scl;
            #pragma unroll
            for (int et = 0; et < 8; ++et) oacc[et] *= scl;
        }
        float rs = 0.f;
        #pragma unroll
        for (int c = 0; c < 2; ++c) {
            #pragma unroll
            for (int reg = 0; reg < 4; ++reg) {
                float p = __expf(sc[c][reg] - mrun);
                sc[c][reg] = p;
                rs += p;
            }
        }
        rs += __shfl_xor(rs, 16);
        rs += __shfl_xor(rs, 32);
        den += rs;

        // ---- issue next tile's global loads (hide under pack + PV) ----
        if (kt + 1 < NT) LOAD_TILE(kt + 1)

        // ---- dropout mask (1/0.9 folded into epilogue) + cvt_pk pack ----
        uint32_t bits = mldsT[kt][w * 16 + r] >> (g * 4);
        float pmv[2][4];
        #pragma unroll
        for (int c = 0; c < 2; ++c) {
            #pragma unroll
            for (int reg = 0; reg < 4; ++reg)
                pmv[c][reg] = ((bits >> (c * 16 + reg)) & 1u) ? sc[c][reg] : 0.0f;
        }
        uint32_t W0 = cvtpk_bf16(pmv[0][0], pmv[0][1]);
        uint32_t W1 = cvtpk_bf16(pmv[0][2], pmv[0][3]);
        uint32_t W2 = cvtpk_bf16(pmv[1][0], pmv[1][1]);
        uint32_t W3 = cvtpk_bf16(pmv[1][2], pmv[1][3]);

        // ---- in-register P^T redistribution (replaces plt LDS roundtrip):
        // dest (g,r) pfrag[j] = W[2*(g>>1)+(j&1)] of lane (2*(g&1)+(j>>1))*16+r
        const int s01 = ((g & 1) << 5) + r;
        const int s23 = s01 + 16;
        uint32_t a0 = (uint32_t)__shfl((int)W0, s01);
        uint32_t a2 = (uint32_t)__shfl((int)W2, s01);
        uint32_t b0 = (uint32_t)__shfl((int)W1, s01);
        uint32_t b2 = (uint32_t)__shfl((int)W3, s01);
        uint32_t c0 = (uint32_t)__shfl((int)W0, s23);
        uint32_t c2 = (uint32_t)__shfl((int)W2, s23);
        uint32_t d0 = (uint32_t)__shfl((int)W1, s23);
        uint32_t d2 = (uint32_t)__shfl((int)W3, s23);
        union { bf16x8 v; uint32_t u[4]; } pf;
        const bool lo = (g < 2);
        pf.u[0] = lo ? a0 : a2;
        pf.u[1] = lo ? b0 : b2;
        pf.u[2] = lo ? c0 : c2;
        pf.u[3] = lo ? d0 : d2;
        bf16x8 pfrag = pf.v;

        // ---- O^T += V^T P^T ----
        const int swr = ((r >> 3) & 1) << 1;
        #pragma unroll
        for (int et = 0; et < 8; ++et) {
            const short* vp = vt + (et * 16 + r) * 40 + ((g ^ swr) << 3);
            bf16x8 av = *(const bf16x8*)vp;
            oacc[et] = __builtin_amdgcn_mfma_f32_16x16x32_bf16(av, pfrag, oacc[et], 0, 0, 0);
        }
    }

    // ---- epilogue: O[q=w*16+r][e=et*16+g*4+reg]; 1/0.9 applied here ----
    const int q = w * 16 + r;             // 0..127
    if (NSPLIT == 1) {
        float inv = (1.0f / 0.9f) / den;
        float* dst = outp + boff + (size_t)(q0 + q) * E_DIM;
        #pragma unroll
        for (int et = 0; et < 8; ++et) {
            f32x4 o = oacc[et] * inv;
            *(f32x4*)(dst + et * 16 + g * 4) = o;
        }
    } else {
        float* pb = outp + (size_t)wg * PART2_FLOATS;
        if (g == 0) {
            pb[q]       = mrun;
            pb[128 + q] = den;
        }
        #pragma unroll
        for (int et = 0; et < 8; ++et)
            *(f32x4*)(pb + 256 + q * E_DIM + et * 16 + g * 4) = oacc[et];
    }
}

// ============ kernel 2: merge NSPLIT partials (applies 1/0.9) =============
template<int NSPLIT>
__global__ __launch_bounds__(256, 8)
void merge9(const float* __restrict__ part, float* __restrict__ Og) {
    const int t = blockIdx.x;             // 256 tiles
    const int b = t >> 4;
    const int q0 = (t & 15) << 7;
    const float* ps[NSPLIT];
    #pragma unroll
    for (int s = 0; s < NSPLIT; ++s)
        ps[s] = part + (size_t)(t * NSPLIT + s) * PART2_FLOATS;
    float* dst = Og + (size_t)b * S_LEN * E_DIM + (size_t)q0 * E_DIM;
    for (int i = 0; i < 64; ++i) {
        int idx = i * 256 + threadIdx.x;
        int row = idx >> 7, e = idx & 127;
        float mm = ps[0][row];
        #pragma unroll
        for (int s = 1; s < NSPLIT; ++s) mm = fmaxf(mm, ps[s][row]);
        float d = 0.f, o = 0.f;
        #pragma unroll
        for (int s = 0; s < NSPLIT; ++s) {
            float sc = __expf(ps[s][row] - mm);
            d += ps[s][128 + row] * sc;
            o += ps[s][256 + row * E_DIM + e] * sc;
        }
        dst[row * E_DIM + e] = (o / d) * (1.0f / 0.9f);
    }
}

// ============ fallback: round-4 mono kernel (certified 409 us) ============
__global__ __launch_bounds__(256, 2)
void attn_mono(const float* __restrict__ Qg, const float* __restrict__ Kg,
               const float* __restrict__ Vg, float* __restrict__ Og) {
    __shared__ short kh[KTM * E_DIM];
    __shared__ short kl[KTM * E_DIM];
    __shared__ short vt[E_DIM * 66];
    __shared__ short pl[4][16 * 64];

    const int tid = threadIdx.x;
    const int w   = tid >> 6;
    const int ln  = tid & 63;
    const int r   = ln & 15;
    const int g   = ln >> 4;
    const int bid = blockIdx.x;
    const int b   = bid >> 5;
    const int q0  = (bid & 31) << 6;
    const size_t boff = (size_t)b * S_LEN * E_DIM;

    {
        const float* src = Qg + boff + (size_t)q0 * E_DIM;
        const int e0 = (tid & 31) * 4;
        const int rb = tid >> 5;
        #pragma unroll
        for (int it = 0; it < 8; ++it) {
            int row = it * 8 + rb;
            f32x4 v = *(const f32x4*)(src + row * E_DIM + e0);
            s16x4 h, lo;
            #pragma unroll
            for (int i = 0; i < 4; ++i) {
                short hh = f2bf(v[i]);
                h[i]  = hh;
                lo[i] = f2bf(v[i] - bf2f(hh));
            }
            int idx = (row * E_DIM + e0) ^ ((row & 7) << 3);
            *(s16x4*)(kh + idx) = h;
            *(s16x4*)(kl + idx) = lo;
        }
    }
    __syncthreads();
    bf16x8 qh[4], ql[4];
    {
        int row = w * 16 + r;
        #pragma unroll
        for (int ec = 0; ec < 4; ++ec) {
            int idx = (row * E_DIM + ec * 32 + g * 8) ^ ((row & 7) << 3);
            qh[ec] = *(const bf16x8*)(kh + idx);
            ql[ec] = *(const bf16x8*)(kl + idx);
        }
    }
    f32x4 oacc[8];
    #pragma unroll
    for (int i = 0; i < 8; ++i) oacc[i] = f32x4{0.f, 0.f, 0.f, 0.f};
    float mrun[4] = {-1e30f, -1e30f, -1e30f, -1e30f};
    float den[4]  = {0.f, 0.f, 0.f, 0.f};

    for (int kt = 0; kt < S_LEN / KTM; ++kt) {
        __syncthreads();
        {
            const float* src = Kg + boff + (size_t)(kt * KTM) * E_DIM;
            const int e0 = (tid & 31) * 4;
            const int rb = tid >> 5;
            #pragma unroll
            for (int it = 0; it < 8; ++it) {
                int row = it * 8 + rb;
                f32x4 v = *(const f32x4*)(src + row * E_DIM + e0);
                s16x4 h, lo;
                #pragma unroll
                for (int i = 0; i < 4; ++i) {
                    short hh = f2bf(v[i]);
                    h[i]  = hh;
                    lo[i] = f2bf(v[i] - bf2f(hh));
                }
                int idx = (row * E_DIM + e0) ^ ((row & 7) << 3);
                *(s16x4*)(kh + idx) = h;
                *(s16x4*)(kl + idx) = lo;
            }
        }
        {
            const float* src = Vg + boff + (size_t)(kt * KTM) * E_DIM;
            const int e0 = (tid & 31) * 4;
            const int kb = (tid >> 5) * 2;
            #pragma unroll
            for (int it = 0; it < 4; ++it) {
                int k = it * 16 + kb;
                f32x4 a  = *(const f32x4*)(src + k * E_DIM + e0);
                f32x4 c2 = *(const f32x4*)(src + (k + 1) * E_DIM + e0);
                #pragma unroll
                for (int ci = 0; ci < 4; ++ci) {
                    uint32_t pack = (uint32_t)(uint16_t)f2bf(a[ci]) |
                                    ((uint32_t)(uint16_t)f2bf(c2[ci]) << 16);
                    *(uint32_t*)(vt + (e0 + ci) * 66 + k) = pack;
                }
            }
        }
        __syncthreads();
        f32x4 sc[4];
        #pragma unroll
        for (int c = 0; c < 4; ++c) {
            f32x4 acc = f32x4{0.f, 0.f, 0.f, 0.f};
            int krow = c * 16 + r;
            int sw = (krow & 7) << 3;
            #pragma unroll
            for (int ec = 0; ec < 4; ++ec) {
                int idx = (krow * E_DIM + ec * 32 + g * 8) ^ sw;
                bf16x8 bh = *(const bf16x8*)(kh + idx);
                bf16x8 bl = *(const bf16x8*)(kl + idx);
                acc = __builtin_amdgcn_mfma_f32_16x16x32_bf16(qh[ec], bh, acc, 0, 0, 0);
                acc = __builtin_amdgcn_mfma_f32_16x16x32_bf16(ql[ec], bh, acc, 0, 0, 0);
                acc = __builtin_amdgcn_mfma_f32_16x16x32_bf16(qh[ec], bl, acc, 0, 0, 0);
            }
            sc[c] = acc;
        }
        float scale[4];
        #pragma unroll
        for (int reg = 0; reg < 4; ++reg) {
            float v0 = fmaxf(fmaxf(sc[0][reg], sc[1][reg]),
                             fmaxf(sc[2][reg], sc[3][reg]));
            v0 = fmaxf(v0, __shfl_xor(v0, 1));
            v0 = fmaxf(v0, __shfl_xor(v0, 2));
            v0 = fmaxf(v0, __shfl_xor(v0, 4));
            v0 = fmaxf(v0, __shfl_xor(v0, 8));
            float mnew = fmaxf(mrun[reg], v0);
            scale[reg] = __expf(mrun[reg] - mnew);
            mrun[reg] = mnew;
        }
        float rs[4] = {0.f, 0.f, 0.f, 0.f};
        #pragma unroll
        for (int c = 0; c < 4; ++c) {
            #pragma unroll
            for (int reg = 0; reg < 4; ++reg) {
                float p = __expf(sc[c][reg] - mrun[reg]);
                sc[c][reg] = p;
                rs[reg] += p;
            }
        }
        #pragma unroll
        for (int reg = 0; reg < 4; ++reg) {
            float v0 = rs[reg];
            v0 += __shfl_xor(v0, 1);
            v0 += __shfl_xor(v0, 2);
            v0 += __shfl_xor(v0, 4);
            v0 += __shfl_xor(v0, 8);
            den[reg] = den[reg] * scale[reg] + v0;
        }
        #pragma unroll
        for (int et = 0; et < 8; ++et) {
            #pragma unroll
            for (int reg = 0; reg < 4; ++reg) oacc[et][reg] *= scale[reg];
        }
        #pragma unroll
        for (int c = 0; c < 4; ++c) {
            int kcol = kt * KTM + c * 16 + r;
            #pragma unroll
            for (int reg = 0; reg < 4; ++reg) {
                int row = g * 4 + reg;
                uint32_t q = (uint32_t)(q0 + w * 16 + row);
                uint32_t j = (((uint32_t)b << 11) + q) * 2048u + (uint32_t)kcol;
                float pm = keep_bit(j) ? sc[c][reg] * (1.0f / 0.9f) : 0.0f;
                int idx = (row * 64 + (c * 16 + r)) ^ ((row & 7) << 3);
                pl[w][idx] = f2bf(pm);
            }
        }
        bf16x8 pa[2];
        #pragma unroll
        for (int st = 0; st < 2; ++st) {
            int idx = (r * 64 + st * 32 + g * 8) ^ ((r & 7) << 3);
            pa[st] = *(const bf16x8*)(&pl[w][0] + idx);
        }
        #pragma unroll
        for (int et = 0; et < 8; ++et) {
            int e = et * 16 + r;
            f32x4 o = oacc[et];
            #pragma unroll
            for (int st = 0; st < 2; ++st) {
                union { bf16x8 v; uint32_t u[4]; } vb;
                #pragma unroll
                for (int i2 = 0; i2 < 4; ++i2)
                    vb.u[i2] = *(const uint32_t*)(vt + e * 66 + st * 32 + g * 8 + i2 * 2);
                o = __builtin_amdgcn_mfma_f32_16x16x32_bf16(pa[st], vb.v, o, 0, 0, 0);
            }
            oacc[et] = o;
        }
    }
    float inv[4];
    #pragma unroll
    for (int reg = 0; reg < 4; ++reg) inv[reg] = 1.0f / den[reg];
    float* dst = Og + boff + (size_t)q0 * E_DIM;
    #pragma unroll
    for (int et = 0; et < 8; ++et) {
        #pragma unroll
        for (int reg = 0; reg < 4; ++reg) {
            int row = w * 16 + g * 4 + reg;
            int e = et * 16 + r;
            dst[row * E_DIM + e] = oacc[et][reg] * inv[reg];
        }
    }
}

extern "C" void kernel_launch(void* const* d_in, const int* in_sizes, int n_in,
                              void* d_out, int out_size, void* d_ws, size_t ws_size,
                              hipStream_t stream) {
    (void)in_sizes; (void)n_in; (void)out_size;
    const float* Q = (const float*)d_in[0];
    const float* K = (const float*)d_in[1];
    const float* V = (const float*)d_in[2];
    float* O = (float*)d_out;
    if (ws_size >= TIER_B) {
        short* KH = (short*)d_ws;
        short* KL = (short*)((char*)d_ws + ARR_BYTES);
        short* VT = (short*)((char*)d_ws + 2u * ARR_BYTES);
        hipLaunchKernelGGL(convert_kv, dim3(512), dim3(256), 0, stream, K, V, KH, KL, VT);
        if (ws_size >= TIER_A4) {
            float* part = (float*)((char*)d_ws + TIER_B);
            hipLaunchKernelGGL((attn10<4>), dim3(1024), dim3(512), 0, stream,
                               Q, KH, KL, VT, part);
            hipLaunchKernelGGL((merge9<4>), dim3(256), dim3(256), 0, stream, part, O);
        } else if (ws_size >= TIER_A2) {
            float* part = (float*)((char*)d_ws + TIER_B);
            hipLaunchKernelGGL((attn10<2>), dim3(512), dim3(512), 0, stream,
                               Q, KH, KL, VT, part);
            hipLaunchKernelGGL((merge9<2>), dim3(256), dim3(256), 0, stream, part, O);
        } else {
            hipLaunchKernelGGL((attn10<1>), dim3(256), dim3(512), 0, stream,
                               Q, KH, KL, VT, O);
        }
    } else {
        hipLaunchKernelGGL(attn_mono, dim3(512), dim3(256), 0, stream, Q, K, V, O);
    }
}

// Round 17
// 247.752 us; speedup vs baseline: 3.2182x; 3.2182x over previous
//
#include <hip/hip_runtime.h>
#include <hip/hip_bf16.h>
#include <stdint.h>

#define S_LEN 2048
#define E_DIM 128
#define KT 32
#define KTM 64   // mono fallback tile

// ws: [0,8Mi) KH | [8Mi,16Mi) KL | [16Mi,24Mi) VT | [24Mi,..) split-K partials
#define ARR_BYTES    (8u * 1024 * 1024)         // 16*2048*128 bf16
#define PART2_FLOATS 16640                      // per block: m[128],den[128],O[128][128]
#define TIER_B       ((size_t)3u * ARR_BYTES)
#define TIER_A2      (TIER_B + (size_t)512 * PART2_FLOATS * 4)   // 59.2MB
#define TIER_A4      (TIER_B + (size_t)1024 * PART2_FLOATS * 4)  // 93.3MB

typedef __attribute__((ext_vector_type(4))) float f32x4;
typedef __attribute__((ext_vector_type(4))) short s16x4;
typedef __attribute__((ext_vector_type(8))) short bf16x8;

__device__ __forceinline__ short f2bf(float f) {
    uint32_t u = __builtin_bit_cast(uint32_t, f);
    u += 0x7FFFu + ((u >> 16) & 1u);
    return (short)(u >> 16);
}
__device__ __forceinline__ float bf2f(short h) {
    uint32_t u = ((uint32_t)(uint16_t)h) << 16;
    return __builtin_bit_cast(float, u);
}
__device__ __forceinline__ uint32_t cvtpk_bf16(float lo, float hi) {
    uint32_t d;
    asm volatile("v_cvt_pk_bf16_f32 %0, %1, %2" : "=v"(d) : "v"(lo), "v"(hi));
    return d;
}

// Threefry-2x32, rotl via v_alignbit (KAT-certified on gfx950 r4/r5)
__device__ __forceinline__ void threefry_g(uint32_t k0, uint32_t k1,
                                           uint32_t c0, uint32_t c1,
                                           uint32_t& y0, uint32_t& y1) {
    uint32_t ks2 = k0 ^ k1 ^ 0x1BD11BDAu;
    uint32_t x0 = c0 + k0, x1 = c1 + k1;
#define TF_R(rr) { x0 += x1; x1 = __builtin_amdgcn_alignbit(x1, x1, 32u - rr); x1 ^= x0; }
    TF_R(13) TF_R(15) TF_R(26) TF_R(6)
    x0 += k1;  x1 += ks2 + 1u;
    TF_R(17) TF_R(29) TF_R(16) TF_R(24)
    x0 += ks2; x1 += k0 + 2u;
    TF_R(13) TF_R(15) TF_R(26) TF_R(6)
    x0 += k0;  x1 += k1 + 3u;
    TF_R(17) TF_R(29) TF_R(16) TF_R(24)
    x0 += k1;  x1 += ks2 + 4u;
    TF_R(13) TF_R(15) TF_R(26) TF_R(6)
    x0 += ks2; x1 += k0 + 5u;
#undef TF_R
    y0 = x0; y1 = x1;
}

// JAX partitionable threefry, x64 off: ctr=(0,j), draw=y0^y1 (certified r4-r16)
__device__ __forceinline__ bool keep_bit(uint32_t j) {
    uint32_t y0, y1;
    threefry_g(0u, 42u, 0u, j, y0, y1);
    return (y0 ^ y1) < 0xE6666600u;
}

// ============ kernel 0: one-time K/V convert (split bf16 + V transpose) ====
__global__ __launch_bounds__(256, 4)
void convert_kv(const float* __restrict__ Kg, const float* __restrict__ Vg,
                short* __restrict__ KH, short* __restrict__ KL,
                short* __restrict__ VT) {
    __shared__ short vs[64][130];
    const int blk = blockIdx.x;           // 512 = 16 b x 32 tiles
    const int b = blk >> 5, t = blk & 31;
    const size_t base = ((size_t)b * S_LEN + (size_t)t * 64) * E_DIM;
    const int e0 = (threadIdx.x & 31) * 4;
    const int rb = threadIdx.x >> 5;
    #pragma unroll
    for (int it = 0; it < 8; ++it) {
        int row = it * 8 + rb;
        f32x4 kv = *(const f32x4*)(Kg + base + row * E_DIM + e0);
        s16x4 h, lo;
        #pragma unroll
        for (int i = 0; i < 4; ++i) {
            short hh = f2bf(kv[i]);
            h[i]  = hh;
            lo[i] = f2bf(kv[i] - bf2f(hh));
        }
        *(s16x4*)(KH + base + row * E_DIM + e0) = h;
        *(s16x4*)(KL + base + row * E_DIM + e0) = lo;
        f32x4 vv = *(const f32x4*)(Vg + base + row * E_DIM + e0);
        #pragma unroll
        for (int i = 0; i < 4; ++i) vs[row][e0 + i] = f2bf(vv[i]);
    }
    __syncthreads();
    const int e = threadIdx.x >> 1;
    const int k2 = (threadIdx.x & 1) * 32;
    short* dst = VT + ((size_t)b * E_DIM + e) * S_LEN + t * 64 + k2;
    #pragma unroll
    for (int i = 0; i < 32; i += 4) {
        s16x4 v;
        #pragma unroll
        for (int q2 = 0; q2 < 4; ++q2) v[q2] = vs[k2 + i + q2][e];
        *(s16x4*)(dst + i) = v;
    }
}

// == kernel 1: QT=128 8-wave swapped attn, shfl P-redistribution (no plt) ===
// launch_bounds (512,4): 128-VGPR budget -> no spill (r16's (512,8) clamped
// to 32 VGPR and spilled 3.2GB to scratch). Occupancy comes from LDS fit.
template<int NSPLIT>
__global__ __launch_bounds__(512, 4)
void attn10(const float* __restrict__ Qg, const short* __restrict__ KH,
            const short* __restrict__ KL, const short* __restrict__ VT,
            float* __restrict__ outp) {
    constexpr int NT = (S_LEN / NSPLIT) / KT;
    __shared__ __attribute__((aligned(16))) short kh[KT * E_DIM];  // 8 KB swz
    __shared__ __attribute__((aligned(16))) short kl[KT * E_DIM];  // 8 KB
    __shared__ __attribute__((aligned(16))) short vt[E_DIM * 40];  // 10 KB
    __shared__ uint32_t mldsT[NT][128];   // NS=4: 8 KB

    const int tid = threadIdx.x;
    const int w   = tid >> 6;             // 0..7
    const int ln  = tid & 63;
    const int r   = ln & 15;
    const int g   = ln >> 4;
    const int nwg = 256 * NSPLIT;
    const int wg  = (blockIdx.x & 7) * (nwg >> 3) + (blockIdx.x >> 3);
    const int t   = wg / NSPLIT;          // 0..255
    const int s   = wg % NSPLIT;
    const int b   = t >> 4;
    const int q0  = (t & 15) << 7;        // 128-row Q tile
    const int k0g = s * (S_LEN / NSPLIT);
    const size_t boff = (size_t)b * S_LEN * E_DIM;

    // ---- Q fragments (B-operand of swapped QK^T), split bf16 in regs ----
    bf16x8 qh[4], ql[4];
    #pragma unroll
    for (int ec = 0; ec < 4; ++ec) {
        const float* src = Qg + boff + (size_t)(q0 + w * 16 + r) * E_DIM + ec * 32 + g * 8;
        f32x4 va = *(const f32x4*)(src);
        f32x4 vb2 = *(const f32x4*)(src + 4);
        #pragma unroll
        for (int i = 0; i < 4; ++i) {
            short hh = f2bf(va[i]);
            qh[ec][i] = hh;
            ql[ec][i] = f2bf(va[i] - bf2f(hh));
            short h2 = f2bf(vb2[i]);
            qh[ec][4 + i] = h2;
            ql[ec][4 + i] = f2bf(vb2[i] - bf2f(h2));
        }
    }

    // ---- mask prologue: wave w rows w*16..+15, transposed store ----
    {
        constexpr int segs = (S_LEN / NSPLIT) / 64;
        const uint32_t jb = (((uint32_t)b << 11) + (uint32_t)q0) * 2048u
                          + (uint32_t)k0g + (uint32_t)ln;
        for (int rr = 0; rr < 16; ++rr) {
            uint32_t jrow = jb + (uint32_t)(w * 16 + rr) * 2048u;
            #pragma unroll
            for (int seg = 0; seg < segs; ++seg) {
                uint64_t m = __ballot(keep_bit(jrow + (uint32_t)(seg * 64)));
                if (ln < 2) mldsT[seg * 2 + ln][w * 16 + rr] = (uint32_t)(m >> (ln * 32));
            }
        }
    }

    const short* KHb = KH + ((size_t)b * S_LEN + k0g) * E_DIM;
    const short* KLb = KL + ((size_t)b * S_LEN + k0g) * E_DIM;
    const short* VTb = VT + (size_t)b * E_DIM * S_LEN + k0g;

    // staging (T14): 512 threads stage one 32x128 K tile + 128x32 V^T tile
    bf16x8 skh, skl, svv;
    const int se0 = (tid & 15) * 8;
    const int srl = tid >> 4;             // k-row 0..31
    const int sve = tid >> 2;             // e 0..127
    const int svq = tid & 3;              // chunk 0..3
#define LOAD_TILE(ktt)                                                          \
    {                                                                           \
        skh = *(const bf16x8*)(KHb + (size_t)((ktt) * KT + srl) * E_DIM + se0); \
        skl = *(const bf16x8*)(KLb + (size_t)((ktt) * KT + srl) * E_DIM + se0); \
        svv = *(const bf16x8*)(VTb + (size_t)sve * S_LEN + (ktt) * KT + svq * 8); \
    }
    LOAD_TILE(0)

    f32x4 oacc[8];
    #pragma unroll
    for (int i = 0; i < 8; ++i) oacc[i] = f32x4{0.f, 0.f, 0.f, 0.f};
    float mrun = -1e30f, den = 0.f;

    for (int kt = 0; kt < NT; ++kt) {
        __syncthreads();   // prev tile's LDS readers done (covers mlds at kt=0)
        // ---- LDS writes of staged regs ----
        {
            int idx = (srl * E_DIM + se0) ^ ((srl & 7) << 3);
            *(bf16x8*)(kh + idx) = skh;
            *(bf16x8*)(kl + idx) = skl;
            const int swv = ((sve >> 3) & 1) << 1;
            *(bf16x8*)(vt + sve * 40 + ((svq ^ swv) << 3)) = svv;
        }
        __syncthreads();

        // ---- S^T = K Q^T: 3-MFMA split (certified r10 numerics) ----
        f32x4 sc[2];
        #pragma unroll
        for (int c = 0; c < 2; ++c) {
            f32x4 acc = f32x4{0.f, 0.f, 0.f, 0.f};
            int krow = c * 16 + r;
            int sw = (krow & 7) << 3;
            #pragma unroll
            for (int ec = 0; ec < 4; ++ec) {
                int idx = (krow * E_DIM + ec * 32 + g * 8) ^ sw;
                bf16x8 bh = *(const bf16x8*)(kh + idx);
                bf16x8 bl = *(const bf16x8*)(kl + idx);
                acc = __builtin_amdgcn_mfma_f32_16x16x32_bf16(bh, qh[ec], acc, 0, 0, 0);
                acc = __builtin_amdgcn_mfma_f32_16x16x32_bf16(bl, qh[ec], acc, 0, 0, 0);
                acc = __builtin_amdgcn_mfma_f32_16x16x32_bf16(bh, ql[ec], acc, 0, 0, 0);
            }
            sc[c] = acc;
        }

        // ---- softmax (per-lane scalar state, 2 shuffles per reduce) ----
        float pmax = fmaxf(fmaxf(fmaxf(sc[0][0], sc[0][1]), fmaxf(sc[0][2], sc[0][3])),
                           fmaxf(fmaxf(sc[1][0], sc[1][1]), fmaxf(sc[1][2], sc[1][3])));
        pmax = fmaxf(pmax, __shfl_xor(pmax, 16));
        pmax = fmaxf(pmax, __shfl_xor(pmax, 32));
        if (__any(pmax - mrun > 8.0f)) {       // defer-max
            float mnew = fmaxf(mrun, pmax);
            float scl = __expf(mrun - mnew);
            mrun = mnew;
            den *= scl;
            #pragma unroll
            for (int et = 0; et < 8; ++et) oacc[et] *= scl;
        }
        float rs = 0.f;
        #pragma unroll
        for (int c = 0; c < 2; ++c) {
            #pragma unroll
            for (int reg = 0; reg < 4; ++reg) {
                float p = __expf(sc[c][reg] - mrun);
                sc[c][reg] = p;
                rs += p;
            }
        }
        rs += __shfl_xor(rs, 16);
        rs += __shfl_xor(rs, 32);
        den += rs;

        // ---- issue next tile's global loads (hide under pack + PV) ----
        if (kt + 1 < NT) LOAD_TILE(kt + 1)

        // ---- dropout mask (1/0.9 folded into epilogue) + cvt_pk pack ----
        uint32_t bits = mldsT[kt][w * 16 + r] >> (g * 4);
        float pmv[2][4];
        #pragma unroll
        for (int c = 0; c < 2; ++c) {
            #pragma unroll
            for (int reg = 0; reg < 4; ++reg)
                pmv[c][reg] = ((bits >> (c * 16 + reg)) & 1u) ? sc[c][reg] : 0.0f;
        }
        uint32_t W0 = cvtpk_bf16(pmv[0][0], pmv[0][1]);
        uint32_t W1 = cvtpk_bf16(pmv[0][2], pmv[0][3]);
        uint32_t W2 = cvtpk_bf16(pmv[1][0], pmv[1][1]);
        uint32_t W3 = cvtpk_bf16(pmv[1][2], pmv[1][3]);

        // ---- in-register P^T redistribution (replaces plt LDS roundtrip):
        // dest (g,r) pfrag[j] = W[2*(g>>1)+(j&1)] of lane (2*(g&1)+(j>>1))*16+r
        const int s01 = ((g & 1) << 5) + r;
        const int s23 = s01 + 16;
        uint32_t a0 = (uint32_t)__shfl((int)W0, s01);
        uint32_t a2 = (uint32_t)__shfl((int)W2, s01);
        uint32_t b0 = (uint32_t)__shfl((int)W1, s01);
        uint32_t b2 = (uint32_t)__shfl((int)W3, s01);
        uint32_t c0 = (uint32_t)__shfl((int)W0, s23);
        uint32_t c2 = (uint32_t)__shfl((int)W2, s23);
        uint32_t d0 = (uint32_t)__shfl((int)W1, s23);
        uint32_t d2 = (uint32_t)__shfl((int)W3, s23);
        union { bf16x8 v; uint32_t u[4]; } pf;
        const bool lo = (g < 2);
        pf.u[0] = lo ? a0 : a2;
        pf.u[1] = lo ? b0 : b2;
        pf.u[2] = lo ? c0 : c2;
        pf.u[3] = lo ? d0 : d2;
        bf16x8 pfrag = pf.v;

        // ---- O^T += V^T P^T ----
        const int swr = ((r >> 3) & 1) << 1;
        #pragma unroll
        for (int et = 0; et < 8; ++et) {
            const short* vp = vt + (et * 16 + r) * 40 + ((g ^ swr) << 3);
            bf16x8 av = *(const bf16x8*)vp;
            oacc[et] = __builtin_amdgcn_mfma_f32_16x16x32_bf16(av, pfrag, oacc[et], 0, 0, 0);
        }
    }

    // ---- epilogue: O[q=w*16+r][e=et*16+g*4+reg]; 1/0.9 applied here ----
    const int q = w * 16 + r;             // 0..127
    if (NSPLIT == 1) {
        float inv = (1.0f / 0.9f) / den;
        float* dst = outp + boff + (size_t)(q0 + q) * E_DIM;
        #pragma unroll
        for (int et = 0; et < 8; ++et) {
            f32x4 o = oacc[et] * inv;
            *(f32x4*)(dst + et * 16 + g * 4) = o;
        }
    } else {
        float* pb = outp + (size_t)wg * PART2_FLOATS;
        if (g == 0) {
            pb[q]       = mrun;
            pb[128 + q] = den;
        }
        #pragma unroll
        for (int et = 0; et < 8; ++et)
            *(f32x4*)(pb + 256 + q * E_DIM + et * 16 + g * 4) = oacc[et];
    }
}

// ============ kernel 2: merge NSPLIT partials (applies 1/0.9) =============
template<int NSPLIT>
__global__ __launch_bounds__(256, 8)
void merge9(const float* __restrict__ part, float* __restrict__ Og) {
    const int t = blockIdx.x;             // 256 tiles
    const int b = t >> 4;
    const int q0 = (t & 15) << 7;
    const float* ps[NSPLIT];
    #pragma unroll
    for (int s = 0; s < NSPLIT; ++s)
        ps[s] = part + (size_t)(t * NSPLIT + s) * PART2_FLOATS;
    float* dst = Og + (size_t)b * S_LEN * E_DIM + (size_t)q0 * E_DIM;
    for (int i = 0; i < 64; ++i) {
        int idx = i * 256 + threadIdx.x;
        int row = idx >> 7, e = idx & 127;
        float mm = ps[0][row];
        #pragma unroll
        for (int s = 1; s < NSPLIT; ++s) mm = fmaxf(mm, ps[s][row]);
        float d = 0.f, o = 0.f;
        #pragma unroll
        for (int s = 0; s < NSPLIT; ++s) {
            float sc = __expf(ps[s][row] - mm);
            d += ps[s][128 + row] * sc;
            o += ps[s][256 + row * E_DIM + e] * sc;
        }
        dst[row * E_DIM + e] = (o / d) * (1.0f / 0.9f);
    }
}

// ============ fallback: round-4 mono kernel (certified 409 us) ============
__global__ __launch_bounds__(256, 2)
void attn_mono(const float* __restrict__ Qg, const float* __restrict__ Kg,
               const float* __restrict__ Vg, float* __restrict__ Og) {
    __shared__ short kh[KTM * E_DIM];
    __shared__ short kl[KTM * E_DIM];
    __shared__ short vt[E_DIM * 66];
    __shared__ short pl[4][16 * 64];

    const int tid = threadIdx.x;
    const int w   = tid >> 6;
    const int ln  = tid & 63;
    const int r   = ln & 15;
    const int g   = ln >> 4;
    const int bid = blockIdx.x;
    const int b   = bid >> 5;
    const int q0  = (bid & 31) << 6;
    const size_t boff = (size_t)b * S_LEN * E_DIM;

    {
        const float* src = Qg + boff + (size_t)q0 * E_DIM;
        const int e0 = (tid & 31) * 4;
        const int rb = tid >> 5;
        #pragma unroll
        for (int it = 0; it < 8; ++it) {
            int row = it * 8 + rb;
            f32x4 v = *(const f32x4*)(src + row * E_DIM + e0);
            s16x4 h, lo;
            #pragma unroll
            for (int i = 0; i < 4; ++i) {
                short hh = f2bf(v[i]);
                h[i]  = hh;
                lo[i] = f2bf(v[i] - bf2f(hh));
            }
            int idx = (row * E_DIM + e0) ^ ((row & 7) << 3);
            *(s16x4*)(kh + idx) = h;
            *(s16x4*)(kl + idx) = lo;
        }
    }
    __syncthreads();
    bf16x8 qh[4], ql[4];
    {
        int row = w * 16 + r;
        #pragma unroll
        for (int ec = 0; ec < 4; ++ec) {
            int idx = (row * E_DIM + ec * 32 + g * 8) ^ ((row & 7) << 3);
            qh[ec] = *(const bf16x8*)(kh + idx);
            ql[ec] = *(const bf16x8*)(kl + idx);
        }
    }
    f32x4 oacc[8];
    #pragma unroll
    for (int i = 0; i < 8; ++i) oacc[i] = f32x4{0.f, 0.f, 0.f, 0.f};
    float mrun[4] = {-1e30f, -1e30f, -1e30f, -1e30f};
    float den[4]  = {0.f, 0.f, 0.f, 0.f};

    for (int kt = 0; kt < S_LEN / KTM; ++kt) {
        __syncthreads();
        {
            const float* src = Kg + boff + (size_t)(kt * KTM) * E_DIM;
            const int e0 = (tid & 31) * 4;
            const int rb = tid >> 5;
            #pragma unroll
            for (int it = 0; it < 8; ++it) {
                int row = it * 8 + rb;
                f32x4 v = *(const f32x4*)(src + row * E_DIM + e0);
                s16x4 h, lo;
                #pragma unroll
                for (int i = 0; i < 4; ++i) {
                    short hh = f2bf(v[i]);
                    h[i]  = hh;
                    lo[i] = f2bf(v[i] - bf2f(hh));
                }
                int idx = (row * E_DIM + e0) ^ ((row & 7) << 3);
                *(s16x4*)(kh + idx) = h;
                *(s16x4*)(kl + idx) = lo;
            }
        }
        {
            const float* src = Vg + boff + (size_t)(kt * KTM) * E_DIM;
            const int e0 = (tid & 31) * 4;
            const int kb = (tid >> 5) * 2;
            #pragma unroll
            for (int it = 0; it < 4; ++it) {
                int k = it * 16 + kb;
                f32x4 a  = *(const f32x4*)(src + k * E_DIM + e0);
                f32x4 c2 = *(const f32x4*)(src + (k + 1) * E_DIM + e0);
                #pragma unroll
                for (int ci = 0; ci < 4; ++ci) {
                    uint32_t pack = (uint32_t)(uint16_t)f2bf(a[ci]) |
                                    ((uint32_t)(uint16_t)f2bf(c2[ci]) << 16);
                    *(uint32_t*)(vt + (e0 + ci) * 66 + k) = pack;
                }
            }
        }
        __syncthreads();
        f32x4 sc[4];
        #pragma unroll
        for (int c = 0; c < 4; ++c) {
            f32x4 acc = f32x4{0.f, 0.f, 0.f, 0.f};
            int krow = c * 16 + r;
            int sw = (krow & 7) << 3;
            #pragma unroll
            for (int ec = 0; ec < 4; ++ec) {
                int idx = (krow * E_DIM + ec * 32 + g * 8) ^ sw;
                bf16x8 bh = *(const bf16x8*)(kh + idx);
                bf16x8 bl = *(const bf16x8*)(kl + idx);
                acc = __builtin_amdgcn_mfma_f32_16x16x32_bf16(qh[ec], bh, acc, 0, 0, 0);
                acc = __builtin_amdgcn_mfma_f32_16x16x32_bf16(ql[ec], bh, acc, 0, 0, 0);
                acc = __builtin_amdgcn_mfma_f32_16x16x32_bf16(qh[ec], bl, acc, 0, 0, 0);
            }
            sc[c] = acc;
        }
        float scale[4];
        #pragma unroll
        for (int reg = 0; reg < 4; ++reg) {
            float v0 = fmaxf(fmaxf(sc[0][reg], sc[1][reg]),
                             fmaxf(sc[2][reg], sc[3][reg]));
            v0 = fmaxf(v0, __shfl_xor(v0, 1));
            v0 = fmaxf(v0, __shfl_xor(v0, 2));
            v0 = fmaxf(v0, __shfl_xor(v0, 4));
            v0 = fmaxf(v0, __shfl_xor(v0, 8));
            float mnew = fmaxf(mrun[reg], v0);
            scale[reg] = __expf(mrun[reg] - mnew);
            mrun[reg] = mnew;
        }
        float rs[4] = {0.f, 0.f, 0.f, 0.f};
        #pragma unroll
        for (int c = 0; c < 4; ++c) {
            #pragma unroll
            for (int reg = 0; reg < 4; ++reg) {
                float p = __expf(sc[c][reg] - mrun[reg]);
                sc[c][reg] = p;
                rs[reg] += p;
            }
        }
        #pragma unroll
        for (int reg = 0; reg < 4; ++reg) {
            float v0 = rs[reg];
            v0 += __shfl_xor(v0, 1);
            v0 += __shfl_xor(v0, 2);
            v0 += __shfl_xor(v0, 4);
            v0 += __shfl_xor(v0, 8);
            den[reg] = den[reg] * scale[reg] + v0;
        }
        #pragma unroll
        for (int et = 0; et < 8; ++et) {
            #pragma unroll
            for (int reg = 0; reg < 4; ++reg) oacc[et][reg] *= scale[reg];
        }
        #pragma unroll
        for (int c = 0; c < 4; ++c) {
            int kcol = kt * KTM + c * 16 + r;
            #pragma unroll
            for (int reg = 0; reg < 4; ++reg) {
                int row = g * 4 + reg;
                uint32_t q = (uint32_t)(q0 + w * 16 + row);
                uint32_t j = (((uint32_t)b << 11) + q) * 2048u + (uint32_t)kcol;
                float pm = keep_bit(j) ? sc[c][reg] * (1.0f / 0.9f) : 0.0f;
                int idx = (row * 64 + (c * 16 + r)) ^ ((row & 7) << 3);
                pl[w][idx] = f2bf(pm);
            }
        }
        bf16x8 pa[2];
        #pragma unroll
        for (int st = 0; st < 2; ++st) {
            int idx = (r * 64 + st * 32 + g * 8) ^ ((r & 7) << 3);
            pa[st] = *(const bf16x8*)(&pl[w][0] + idx);
        }
        #pragma unroll
        for (int et = 0; et < 8; ++et) {
            int e = et * 16 + r;
            f32x4 o = oacc[et];
            #pragma unroll
            for (int st = 0; st < 2; ++st) {
                union { bf16x8 v; uint32_t u[4]; } vb;
                #pragma unroll
                for (int i2 = 0; i2 < 4; ++i2)
                    vb.u[i2] = *(const uint32_t*)(vt + e * 66 + st * 32 + g * 8 + i2 * 2);
                o = __builtin_amdgcn_mfma_f32_16x16x32_bf16(pa[st], vb.v, o, 0, 0, 0);
            }
            oacc[et] = o;
        }
    }
    float inv[4];
    #pragma unroll
    for (int reg = 0; reg < 4; ++reg) inv[reg] = 1.0f / den[reg];
    float* dst = Og + boff + (size_t)q0 * E_DIM;
    #pragma unroll
    for (int et = 0; et < 8; ++et) {
        #pragma unroll
        for (int reg = 0; reg < 4; ++reg) {
            int row = w * 16 + g * 4 + reg;
            int e = et * 16 + r;
            dst[row * E_DIM + e] = oacc[et][reg] * inv[reg];
        }
    }
}

extern "C" void kernel_launch(void* const* d_in, const int* in_sizes, int n_in,
                              void* d_out, int out_size, void* d_ws, size_t ws_size,
                              hipStream_t stream) {
    (void)in_sizes; (void)n_in; (void)out_size;
    const float* Q = (const float*)d_in[0];
    const float* K = (const float*)d_in[1];
    const float* V = (const float*)d_in[2];
    float* O = (float*)d_out;
    if (ws_size >= TIER_B) {
        short* KH = (short*)d_ws;
        short* KL = (short*)((char*)d_ws + ARR_BYTES);
        short* VT = (short*)((char*)d_ws + 2u * ARR_BYTES);
        hipLaunchKernelGGL(convert_kv, dim3(512), dim3(256), 0, stream, K, V, KH, KL, VT);
        if (ws_size >= TIER_A4) {
            float* part = (float*)((char*)d_ws + TIER_B);
            hipLaunchKernelGGL((attn10<4>), dim3(1024), dim3(512), 0, stream,
                               Q, KH, KL, VT, part);
            hipLaunchKernelGGL((merge9<4>), dim3(256), dim3(256), 0, stream, part, O);
        } else if (ws_size >= TIER_A2) {
            float* part = (float*)((char*)d_ws + TIER_B);
            hipLaunchKernelGGL((attn10<2>), dim3(512), dim3(512), 0, stream,
                               Q, KH, KL, VT, part);
            hipLaunchKernelGGL((merge9<2>), dim3(256), dim3(256), 0, stream, part, O);
        } else {
            hipLaunchKernelGGL((attn10<1>), dim3(256), dim3(512), 0, stream,
                               Q, KH, KL, VT, O);
        }
    } else {
        hipLaunchKernelGGL(attn_mono, dim3(512), dim3(256), 0, stream, Q, K, V, O);
    }
}

// Round 18
// 246.783 us; speedup vs baseline: 3.2309x; 1.0039x over previous
//
#include <hip/hip_runtime.h>
#include <hip/hip_bf16.h>
#include <stdint.h>

#define S_LEN 2048
#define E_DIM 128
#define KT 32
#define KTM 64   // mono fallback tile

// ws: [0,8Mi) KH | [8Mi,16Mi) KL | [16Mi,24Mi) VT | [24Mi,..) split-K partials
#define ARR_BYTES    (8u * 1024 * 1024)         // 16*2048*128 bf16
#define PART2_FLOATS 16640                      // per block: m[128],den[128],O[128][128]
#define TIER_B       ((size_t)3u * ARR_BYTES)
#define TIER_A2      (TIER_B + (size_t)512 * PART2_FLOATS * 4)   // 59.2MB
#define TIER_A4      (TIER_B + (size_t)1024 * PART2_FLOATS * 4)  // 93.3MB

typedef __attribute__((ext_vector_type(4))) float f32x4;
typedef __attribute__((ext_vector_type(4))) short s16x4;
typedef __attribute__((ext_vector_type(8))) short bf16x8;

__device__ __forceinline__ short f2bf(float f) {
    uint32_t u = __builtin_bit_cast(uint32_t, f);
    u += 0x7FFFu + ((u >> 16) & 1u);
    return (short)(u >> 16);
}
__device__ __forceinline__ float bf2f(short h) {
    uint32_t u = ((uint32_t)(uint16_t)h) << 16;
    return __builtin_bit_cast(float, u);
}
__device__ __forceinline__ uint32_t cvtpk_bf16(float lo, float hi) {
    uint32_t d;
    asm volatile("v_cvt_pk_bf16_f32 %0, %1, %2" : "=v"(d) : "v"(lo), "v"(hi));
    return d;
}

// Threefry-2x32, rotl via v_alignbit (KAT-certified on gfx950 r4/r5)
__device__ __forceinline__ void threefry_g(uint32_t k0, uint32_t k1,
                                           uint32_t c0, uint32_t c1,
                                           uint32_t& y0, uint32_t& y1) {
    uint32_t ks2 = k0 ^ k1 ^ 0x1BD11BDAu;
    uint32_t x0 = c0 + k0, x1 = c1 + k1;
#define TF_R(rr) { x0 += x1; x1 = __builtin_amdgcn_alignbit(x1, x1, 32u - rr); x1 ^= x0; }
    TF_R(13) TF_R(15) TF_R(26) TF_R(6)
    x0 += k1;  x1 += ks2 + 1u;
    TF_R(17) TF_R(29) TF_R(16) TF_R(24)
    x0 += ks2; x1 += k0 + 2u;
    TF_R(13) TF_R(15) TF_R(26) TF_R(6)
    x0 += k0;  x1 += k1 + 3u;
    TF_R(17) TF_R(29) TF_R(16) TF_R(24)
    x0 += k1;  x1 += ks2 + 4u;
    TF_R(13) TF_R(15) TF_R(26) TF_R(6)
    x0 += ks2; x1 += k0 + 5u;
#undef TF_R
    y0 = x0; y1 = x1;
}

// JAX partitionable threefry, x64 off: ctr=(0,j), draw=y0^y1 (certified r4-r17)
__device__ __forceinline__ bool keep_bit(uint32_t j) {
    uint32_t y0, y1;
    threefry_g(0u, 42u, 0u, j, y0, y1);
    return (y0 ^ y1) < 0xE6666600u;
}

// ============ kernel 0: one-time K/V convert (split bf16 + V transpose) ====
__global__ __launch_bounds__(256, 4)
void convert_kv(const float* __restrict__ Kg, const float* __restrict__ Vg,
                short* __restrict__ KH, short* __restrict__ KL,
                short* __restrict__ VT) {
    __shared__ short vs[64][130];
    const int blk = blockIdx.x;           // 512 = 16 b x 32 tiles
    const int b = blk >> 5, t = blk & 31;
    const size_t base = ((size_t)b * S_LEN + (size_t)t * 64) * E_DIM;
    const int e0 = (threadIdx.x & 31) * 4;
    const int rb = threadIdx.x >> 5;
    #pragma unroll
    for (int it = 0; it < 8; ++it) {
        int row = it * 8 + rb;
        f32x4 kv = *(const f32x4*)(Kg + base + row * E_DIM + e0);
        s16x4 h, lo;
        #pragma unroll
        for (int i = 0; i < 4; ++i) {
            short hh = f2bf(kv[i]);
            h[i]  = hh;
            lo[i] = f2bf(kv[i] - bf2f(hh));
        }
        *(s16x4*)(KH + base + row * E_DIM + e0) = h;
        *(s16x4*)(KL + base + row * E_DIM + e0) = lo;
        f32x4 vv = *(const f32x4*)(Vg + base + row * E_DIM + e0);
        #pragma unroll
        for (int i = 0; i < 4; ++i) vs[row][e0 + i] = f2bf(vv[i]);
    }
    __syncthreads();
    const int e = threadIdx.x >> 1;
    const int k2 = (threadIdx.x & 1) * 32;
    short* dst = VT + ((size_t)b * E_DIM + e) * S_LEN + t * 64 + k2;
    #pragma unroll
    for (int i = 0; i < 32; i += 4) {
        s16x4 v;
        #pragma unroll
        for (int q2 = 0; q2 < 4; ++q2) v[q2] = vs[k2 + i + q2][e];
        *(s16x4*)(dst + i) = v;
    }
}

// ===== kernel 1: QT=128 8-wave swapped attn (r15 structure) + setprio ======
template<int NSPLIT>
__global__ __launch_bounds__(512, 4)
void attn11(const float* __restrict__ Qg, const short* __restrict__ KH,
            const short* __restrict__ KL, const short* __restrict__ VT,
            float* __restrict__ outp) {
    constexpr int NT = (S_LEN / NSPLIT) / KT;
    __shared__ __attribute__((aligned(16))) short kh[KT * E_DIM];  // 8 KB swz
    __shared__ __attribute__((aligned(16))) short kl[KT * E_DIM];  // 8 KB
    __shared__ __attribute__((aligned(16))) short vt[E_DIM * 40];  // 10 KB
    __shared__ __attribute__((aligned(16))) uint32_t plt[8][16 * 20]; // 10 KB
    __shared__ uint32_t mldsT[NT][128];   // NS=4: 8 KB

    const int tid = threadIdx.x;
    const int w   = tid >> 6;             // 0..7
    const int ln  = tid & 63;
    const int r   = ln & 15;
    const int g   = ln >> 4;
    const int nwg = 256 * NSPLIT;
    const int wg  = (blockIdx.x & 7) * (nwg >> 3) + (blockIdx.x >> 3);
    const int t   = wg / NSPLIT;          // 0..255
    const int s   = wg % NSPLIT;
    const int b   = t >> 4;
    const int q0  = (t & 15) << 7;        // 128-row Q tile
    const int k0g = s * (S_LEN / NSPLIT);
    const size_t boff = (size_t)b * S_LEN * E_DIM;

    // ---- Q fragments (B-operand of swapped QK^T), split bf16 in regs ----
    bf16x8 qh[4], ql[4];
    #pragma unroll
    for (int ec = 0; ec < 4; ++ec) {
        const float* src = Qg + boff + (size_t)(q0 + w * 16 + r) * E_DIM + ec * 32 + g * 8;
        f32x4 va = *(const f32x4*)(src);
        f32x4 vb2 = *(const f32x4*)(src + 4);
        #pragma unroll
        for (int i = 0; i < 4; ++i) {
            short hh = f2bf(va[i]);
            qh[ec][i] = hh;
            ql[ec][i] = f2bf(va[i] - bf2f(hh));
            short h2 = f2bf(vb2[i]);
            qh[ec][4 + i] = h2;
            ql[ec][4 + i] = f2bf(vb2[i] - bf2f(h2));
        }
    }

    // ---- mask prologue: wave w covers rows w*16..+15, transposed store ----
    {
        constexpr int segs = (S_LEN / NSPLIT) / 64;
        const uint32_t jb = (((uint32_t)b << 11) + (uint32_t)q0) * 2048u
                          + (uint32_t)k0g + (uint32_t)ln;
        for (int rr = 0; rr < 16; ++rr) {
            uint32_t jrow = jb + (uint32_t)(w * 16 + rr) * 2048u;
            #pragma unroll
            for (int seg = 0; seg < segs; ++seg) {
                uint64_t m = __ballot(keep_bit(jrow + (uint32_t)(seg * 64)));
                if (ln < 2) mldsT[seg * 2 + ln][w * 16 + rr] = (uint32_t)(m >> (ln * 32));
            }
        }
    }

    const short* KHb = KH + ((size_t)b * S_LEN + k0g) * E_DIM;
    const short* KLb = KL + ((size_t)b * S_LEN + k0g) * E_DIM;
    const short* VTb = VT + (size_t)b * E_DIM * S_LEN + k0g;

    // staging (T14): 512 threads stage one 32x128 K tile + 128x32 V^T tile
    bf16x8 skh, skl, svv;
    const int se0 = (tid & 15) * 8;
    const int srl = tid >> 4;             // k-row 0..31
    const int sve = tid >> 2;             // e 0..127
    const int svq = tid & 3;              // chunk 0..3
#define LOAD_TILE(ktt)                                                          \
    {                                                                           \
        skh = *(const bf16x8*)(KHb + (size_t)((ktt) * KT + srl) * E_DIM + se0); \
        skl = *(const bf16x8*)(KLb + (size_t)((ktt) * KT + srl) * E_DIM + se0); \
        svv = *(const bf16x8*)(VTb + (size_t)sve * S_LEN + (ktt) * KT + svq * 8); \
    }
    LOAD_TILE(0)

    f32x4 oacc[8];
    #pragma unroll
    for (int i = 0; i < 8; ++i) oacc[i] = f32x4{0.f, 0.f, 0.f, 0.f};
    float mrun = -1e30f, den = 0.f;

    for (int kt = 0; kt < NT; ++kt) {
        __syncthreads();   // prev tile's LDS readers done (covers mlds at kt=0)
        // ---- LDS writes of staged regs ----
        {
            int idx = (srl * E_DIM + se0) ^ ((srl & 7) << 3);
            *(bf16x8*)(kh + idx) = skh;
            *(bf16x8*)(kl + idx) = skl;
            const int swv = ((sve >> 3) & 1) << 1;
            *(bf16x8*)(vt + sve * 40 + ((svq ^ swv) << 3)) = svv;
        }
        __syncthreads();

        // ---- S^T = K Q^T: 3-MFMA split (certified r10 numerics); T5 prio ---
        f32x4 sc[2];
        __builtin_amdgcn_s_setprio(1);
        #pragma unroll
        for (int c = 0; c < 2; ++c) {
            f32x4 acc = f32x4{0.f, 0.f, 0.f, 0.f};
            int krow = c * 16 + r;
            int sw = (krow & 7) << 3;
            #pragma unroll
            for (int ec = 0; ec < 4; ++ec) {
                int idx = (krow * E_DIM + ec * 32 + g * 8) ^ sw;
                bf16x8 bh = *(const bf16x8*)(kh + idx);
                bf16x8 bl = *(const bf16x8*)(kl + idx);
                acc = __builtin_amdgcn_mfma_f32_16x16x32_bf16(bh, qh[ec], acc, 0, 0, 0);
                acc = __builtin_amdgcn_mfma_f32_16x16x32_bf16(bl, qh[ec], acc, 0, 0, 0);
                acc = __builtin_amdgcn_mfma_f32_16x16x32_bf16(bh, ql[ec], acc, 0, 0, 0);
            }
            sc[c] = acc;
        }
        __builtin_amdgcn_s_setprio(0);

        // ---- softmax (per-lane scalar state, 2 shuffles per reduce) ----
        float pmax = fmaxf(fmaxf(fmaxf(sc[0][0], sc[0][1]), fmaxf(sc[0][2], sc[0][3])),
                           fmaxf(fmaxf(sc[1][0], sc[1][1]), fmaxf(sc[1][2], sc[1][3])));
        pmax = fmaxf(pmax, __shfl_xor(pmax, 16));
        pmax = fmaxf(pmax, __shfl_xor(pmax, 32));
        if (__any(pmax - mrun > 8.0f)) {       // defer-max
            float mnew = fmaxf(mrun, pmax);
            float scl = __expf(mrun - mnew);
            mrun = mnew;
            den *= scl;
            #pragma unroll
            for (int et = 0; et < 8; ++et) oacc[et] *= scl;
        }
        float rs = 0.f;
        #pragma unroll
        for (int c = 0; c < 2; ++c) {
            #pragma unroll
            for (int reg = 0; reg < 4; ++reg) {
                float p = __expf(sc[c][reg] - mrun);
                sc[c][reg] = p;
                rs += p;
            }
        }
        rs += __shfl_xor(rs, 16);
        rs += __shfl_xor(rs, 32);
        den += rs;

        // ---- issue next tile's global loads (hide under pack + PV) ----
        if (kt + 1 < NT) LOAD_TILE(kt + 1)

        // ---- dropout bits + cvt_pk pack + P^T roundtrip (per-wave LDS) ----
        uint32_t bits = mldsT[kt][w * 16 + r] >> (g * 4);
        float pm[2][4];
        #pragma unroll
        for (int c = 0; c < 2; ++c) {
            #pragma unroll
            for (int reg = 0; reg < 4; ++reg)
                pm[c][reg] = ((bits >> (c * 16 + reg)) & 1u)
                               ? sc[c][reg] * (1.0f / 0.9f) : 0.0f;
        }
        uint2 pk0 = { cvtpk_bf16(pm[0][0], pm[0][1]), cvtpk_bf16(pm[0][2], pm[0][3]) };
        uint2 pk1 = { cvtpk_bf16(pm[1][0], pm[1][1]), cvtpk_bf16(pm[1][2], pm[1][3]) };
        *(uint2*)(&plt[w][r * 20 + g * 2])     = pk0;
        *(uint2*)(&plt[w][r * 20 + 8 + g * 2]) = pk1;
        bf16x8 pfrag = *(const bf16x8*)((const short*)&plt[w][0] + r * 40 + g * 8);

        // ---- O^T += V^T P^T; T5 prio around MFMA cluster ----
        const int swr = ((r >> 3) & 1) << 1;
        __builtin_amdgcn_s_setprio(1);
        #pragma unroll
        for (int et = 0; et < 8; ++et) {
            const short* vp = vt + (et * 16 + r) * 40 + ((g ^ swr) << 3);
            bf16x8 av = *(const bf16x8*)vp;
            oacc[et] = __builtin_amdgcn_mfma_f32_16x16x32_bf16(av, pfrag, oacc[et], 0, 0, 0);
        }
        __builtin_amdgcn_s_setprio(0);
    }

    // ---- epilogue: O[q=w*16+r][e=et*16+g*4+reg] ----
    const int q = w * 16 + r;             // 0..127
    if (NSPLIT == 1) {
        float inv = 1.0f / den;
        float* dst = outp + boff + (size_t)(q0 + q) * E_DIM;
        #pragma unroll
        for (int et = 0; et < 8; ++et) {
            f32x4 o = oacc[et] * inv;
            *(f32x4*)(dst + et * 16 + g * 4) = o;
        }
    } else {
        float* pb = outp + (size_t)wg * PART2_FLOATS;
        if (g == 0) {
            pb[q]       = mrun;
            pb[128 + q] = den;
        }
        #pragma unroll
        for (int et = 0; et < 8; ++et)
            *(f32x4*)(pb + 256 + q * E_DIM + et * 16 + g * 4) = oacc[et];
    }
}

// ============ kernel 2: merge NSPLIT partials per 128-row tile =============
template<int NSPLIT>
__global__ __launch_bounds__(256, 8)
void merge9(const float* __restrict__ part, float* __restrict__ Og) {
    const int t = blockIdx.x;             // 256 tiles
    const int b = t >> 4;
    const int q0 = (t & 15) << 7;
    const float* ps[NSPLIT];
    #pragma unroll
    for (int s = 0; s < NSPLIT; ++s)
        ps[s] = part + (size_t)(t * NSPLIT + s) * PART2_FLOATS;
    float* dst = Og + (size_t)b * S_LEN * E_DIM + (size_t)q0 * E_DIM;
    for (int i = 0; i < 64; ++i) {
        int idx = i * 256 + threadIdx.x;
        int row = idx >> 7, e = idx & 127;
        float mm = ps[0][row];
        #pragma unroll
        for (int s = 1; s < NSPLIT; ++s) mm = fmaxf(mm, ps[s][row]);
        float d = 0.f, o = 0.f;
        #pragma unroll
        for (int s = 0; s < NSPLIT; ++s) {
            float sc = __expf(ps[s][row] - mm);
            d += ps[s][128 + row] * sc;
            o += ps[s][256 + row * E_DIM + e] * sc;
        }
        dst[row * E_DIM + e] = o / d;
    }
}

// ============ fallback: round-4 mono kernel (certified 409 us) ============
__global__ __launch_bounds__(256, 2)
void attn_mono(const float* __restrict__ Qg, const float* __restrict__ Kg,
               const float* __restrict__ Vg, float* __restrict__ Og) {
    __shared__ short kh[KTM * E_DIM];
    __shared__ short kl[KTM * E_DIM];
    __shared__ short vt[E_DIM * 66];
    __shared__ short pl[4][16 * 64];

    const int tid = threadIdx.x;
    const int w   = tid >> 6;
    const int ln  = tid & 63;
    const int r   = ln & 15;
    const int g   = ln >> 4;
    const int bid = blockIdx.x;
    const int b   = bid >> 5;
    const int q0  = (bid & 31) << 6;
    const size_t boff = (size_t)b * S_LEN * E_DIM;

    {
        const float* src = Qg + boff + (size_t)q0 * E_DIM;
        const int e0 = (tid & 31) * 4;
        const int rb = tid >> 5;
        #pragma unroll
        for (int it = 0; it < 8; ++it) {
            int row = it * 8 + rb;
            f32x4 v = *(const f32x4*)(src + row * E_DIM + e0);
            s16x4 h, lo;
            #pragma unroll
            for (int i = 0; i < 4; ++i) {
                short hh = f2bf(v[i]);
                h[i]  = hh;
                lo[i] = f2bf(v[i] - bf2f(hh));
            }
            int idx = (row * E_DIM + e0) ^ ((row & 7) << 3);
            *(s16x4*)(kh + idx) = h;
            *(s16x4*)(kl + idx) = lo;
        }
    }
    __syncthreads();
    bf16x8 qh[4], ql[4];
    {
        int row = w * 16 + r;
        #pragma unroll
        for (int ec = 0; ec < 4; ++ec) {
            int idx = (row * E_DIM + ec * 32 + g * 8) ^ ((row & 7) << 3);
            qh[ec] = *(const bf16x8*)(kh + idx);
            ql[ec] = *(const bf16x8*)(kl + idx);
        }
    }
    f32x4 oacc[8];
    #pragma unroll
    for (int i = 0; i < 8; ++i) oacc[i] = f32x4{0.f, 0.f, 0.f, 0.f};
    float mrun[4] = {-1e30f, -1e30f, -1e30f, -1e30f};
    float den[4]  = {0.f, 0.f, 0.f, 0.f};

    for (int kt = 0; kt < S_LEN / KTM; ++kt) {
        __syncthreads();
        {
            const float* src = Kg + boff + (size_t)(kt * KTM) * E_DIM;
            const int e0 = (tid & 31) * 4;
            const int rb = tid >> 5;
            #pragma unroll
            for (int it = 0; it < 8; ++it) {
                int row = it * 8 + rb;
                f32x4 v = *(const f32x4*)(src + row * E_DIM + e0);
                s16x4 h, lo;
                #pragma unroll
                for (int i = 0; i < 4; ++i) {
                    short hh = f2bf(v[i]);
                    h[i]  = hh;
                    lo[i] = f2bf(v[i] - bf2f(hh));
                }
                int idx = (row * E_DIM + e0) ^ ((row & 7) << 3);
                *(s16x4*)(kh + idx) = h;
                *(s16x4*)(kl + idx) = lo;
            }
        }
        {
            const float* src = Vg + boff + (size_t)(kt * KTM) * E_DIM;
            const int e0 = (tid & 31) * 4;
            const int kb = (tid >> 5) * 2;
            #pragma unroll
            for (int it = 0; it < 4; ++it) {
                int k = it * 16 + kb;
                f32x4 a  = *(const f32x4*)(src + k * E_DIM + e0);
                f32x4 c2 = *(const f32x4*)(src + (k + 1) * E_DIM + e0);
                #pragma unroll
                for (int ci = 0; ci < 4; ++ci) {
                    uint32_t pack = (uint32_t)(uint16_t)f2bf(a[ci]) |
                                    ((uint32_t)(uint16_t)f2bf(c2[ci]) << 16);
                    *(uint32_t*)(vt + (e0 + ci) * 66 + k) = pack;
                }
            }
        }
        __syncthreads();
        f32x4 sc[4];
        #pragma unroll
        for (int c = 0; c < 4; ++c) {
            f32x4 acc = f32x4{0.f, 0.f, 0.f, 0.f};
            int krow = c * 16 + r;
            int sw = (krow & 7) << 3;
            #pragma unroll
            for (int ec = 0; ec < 4; ++ec) {
                int idx = (krow * E_DIM + ec * 32 + g * 8) ^ sw;
                bf16x8 bh = *(const bf16x8*)(kh + idx);
                bf16x8 bl = *(const bf16x8*)(kl + idx);
                acc = __builtin_amdgcn_mfma_f32_16x16x32_bf16(qh[ec], bh, acc, 0, 0, 0);
                acc = __builtin_amdgcn_mfma_f32_16x16x32_bf16(ql[ec], bh, acc, 0, 0, 0);
                acc = __builtin_amdgcn_mfma_f32_16x16x32_bf16(qh[ec], bl, acc, 0, 0, 0);
            }
            sc[c] = acc;
        }
        float scale[4];
        #pragma unroll
        for (int reg = 0; reg < 4; ++reg) {
            float v0 = fmaxf(fmaxf(sc[0][reg], sc[1][reg]),
                             fmaxf(sc[2][reg], sc[3][reg]));
            v0 = fmaxf(v0, __shfl_xor(v0, 1));
            v0 = fmaxf(v0, __shfl_xor(v0, 2));
            v0 = fmaxf(v0, __shfl_xor(v0, 4));
            v0 = fmaxf(v0, __shfl_xor(v0, 8));
            float mnew = fmaxf(mrun[reg], v0);
            scale[reg] = __expf(mrun[reg] - mnew);
            mrun[reg] = mnew;
        }
        float rs[4] = {0.f, 0.f, 0.f, 0.f};
        #pragma unroll
        for (int c = 0; c < 4; ++c) {
            #pragma unroll
            for (int reg = 0; reg < 4; ++reg) {
                float p = __expf(sc[c][reg] - mrun[reg]);
                sc[c][reg] = p;
                rs[reg] += p;
            }
        }
        #pragma unroll
        for (int reg = 0; reg < 4; ++reg) {
            float v0 = rs[reg];
            v0 += __shfl_xor(v0, 1);
            v0 += __shfl_xor(v0, 2);
            v0 += __shfl_xor(v0, 4);
            v0 += __shfl_xor(v0, 8);
            den[reg] = den[reg] * scale[reg] + v0;
        }
        #pragma unroll
        for (int et = 0; et < 8; ++et) {
            #pragma unroll
            for (int reg = 0; reg < 4; ++reg) oacc[et][reg] *= scale[reg];
        }
        #pragma unroll
        for (int c = 0; c < 4; ++c) {
            int kcol = kt * KTM + c * 16 + r;
            #pragma unroll
            for (int reg = 0; reg < 4; ++reg) {
                int row = g * 4 + reg;
                uint32_t q = (uint32_t)(q0 + w * 16 + row);
                uint32_t j = (((uint32_t)b << 11) + q) * 2048u + (uint32_t)kcol;
                float pm = keep_bit(j) ? sc[c][reg] * (1.0f / 0.9f) : 0.0f;
                int idx = (row * 64 + (c * 16 + r)) ^ ((row & 7) << 3);
                pl[w][idx] = f2bf(pm);
            }
        }
        bf16x8 pa[2];
        #pragma unroll
        for (int st = 0; st < 2; ++st) {
            int idx = (r * 64 + st * 32 + g * 8) ^ ((r & 7) << 3);
            pa[st] = *(const bf16x8*)(&pl[w][0] + idx);
        }
        #pragma unroll
        for (int et = 0; et < 8; ++et) {
            int e = et * 16 + r;
            f32x4 o = oacc[et];
            #pragma unroll
            for (int st = 0; st < 2; ++st) {
                union { bf16x8 v; uint32_t u[4]; } vb;
                #pragma unroll
                for (int i2 = 0; i2 < 4; ++i2)
                    vb.u[i2] = *(const uint32_t*)(vt + e * 66 + st * 32 + g * 8 + i2 * 2);
                o = __builtin_amdgcn_mfma_f32_16x16x32_bf16(pa[st], vb.v, o, 0, 0, 0);
            }
            oacc[et] = o;
        }
    }
    float inv[4];
    #pragma unroll
    for (int reg = 0; reg < 4; ++reg) inv[reg] = 1.0f / den[reg];
    float* dst = Og + boff + (size_t)q0 * E_DIM;
    #pragma unroll
    for (int et = 0; et < 8; ++et) {
        #pragma unroll
        for (int reg = 0; reg < 4; ++reg) {
            int row = w * 16 + g * 4 + reg;
            int e = et * 16 + r;
            dst[row * E_DIM + e] = oacc[et][reg] * inv[reg];
        }
    }
}

extern "C" void kernel_launch(void* const* d_in, const int* in_sizes, int n_in,
                              void* d_out, int out_size, void* d_ws, size_t ws_size,
                              hipStream_t stream) {
    (void)in_sizes; (void)n_in; (void)out_size;
    const float* Q = (const float*)d_in[0];
    const float* K = (const float*)d_in[1];
    const float* V = (const float*)d_in[2];
    float* O = (float*)d_out;
    if (ws_size >= TIER_B) {
        short* KH = (short*)d_ws;
        short* KL = (short*)((char*)d_ws + ARR_BYTES);
        short* VT = (short*)((char*)d_ws + 2u * ARR_BYTES);
        hipLaunchKernelGGL(convert_kv, dim3(512), dim3(256), 0, stream, K, V, KH, KL, VT);
        if (ws_size >= TIER_A4) {
            float* part = (float*)((char*)d_ws + TIER_B);
            hipLaunchKernelGGL((attn11<4>), dim3(1024), dim3(512), 0, stream,
                               Q, KH, KL, VT, part);
            hipLaunchKernelGGL((merge9<4>), dim3(256), dim3(256), 0, stream, part, O);
        } else if (ws_size >= TIER_A2) {
            float* part = (float*)((char*)d_ws + TIER_B);
            hipLaunchKernelGGL((attn11<2>), dim3(512), dim3(512), 0, stream,
                               Q, KH, KL, VT, part);
            hipLaunchKernelGGL((merge9<2>), dim3(256), dim3(256), 0, stream, part, O);
        } else {
            hipLaunchKernelGGL((attn11<1>), dim3(256), dim3(512), 0, stream,
                               Q, KH, KL, VT, O);
        }
    } else {
        hipLaunchKernelGGL(attn_mono, dim3(512), dim3(256), 0, stream, Q, K, V, O);
    }
}

// Round 19
// 221.691 us; speedup vs baseline: 3.5965x; 1.1132x over previous
//
#include <hip/hip_runtime.h>
#include <hip/hip_bf16.h>
#include <stdint.h>

#define S_LEN 2048
#define E_DIM 128
#define KT 32
#define KTM 64   // mono fallback tile

// ws: [0,8Mi) KH | [8Mi,16Mi) KL | [16Mi,24Mi) VT | [24Mi,..) split-K partials
#define ARR_BYTES    (8u * 1024 * 1024)         // 16*2048*128 bf16
#define PART2_FLOATS 16640                      // per block: m[128],den[128],O[128][128]
#define TIER_B       ((size_t)3u * ARR_BYTES)
#define TIER_A2      (TIER_B + (size_t)512 * PART2_FLOATS * 4)   // == r10 tier (59.2MB)
#define TIER_A4      (TIER_B + (size_t)1024 * PART2_FLOATS * 4)  // 93.3MB

typedef __attribute__((ext_vector_type(4))) float f32x4;
typedef __attribute__((ext_vector_type(4))) short s16x4;
typedef __attribute__((ext_vector_type(8))) short bf16x8;

__device__ __forceinline__ short f2bf(float f) {
    uint32_t u = __builtin_bit_cast(uint32_t, f);
    u += 0x7FFFu + ((u >> 16) & 1u);
    return (short)(u >> 16);
}
__device__ __forceinline__ float bf2f(short h) {
    uint32_t u = ((uint32_t)(uint16_t)h) << 16;
    return __builtin_bit_cast(float, u);
}
__device__ __forceinline__ uint32_t cvtpk_bf16(float lo, float hi) {
    uint32_t d;
    asm volatile("v_cvt_pk_bf16_f32 %0, %1, %2" : "=v"(d) : "v"(lo), "v"(hi));
    return d;
}

// Threefry-2x32, rotl via v_alignbit (KAT-certified on gfx950 r4/r5)
__device__ __forceinline__ void threefry_g(uint32_t k0, uint32_t k1,
                                           uint32_t c0, uint32_t c1,
                                           uint32_t& y0, uint32_t& y1) {
    uint32_t ks2 = k0 ^ k1 ^ 0x1BD11BDAu;
    uint32_t x0 = c0 + k0, x1 = c1 + k1;
#define TF_R(rr) { x0 += x1; x1 = __builtin_amdgcn_alignbit(x1, x1, 32u - rr); x1 ^= x0; }
    TF_R(13) TF_R(15) TF_R(26) TF_R(6)
    x0 += k1;  x1 += ks2 + 1u;
    TF_R(17) TF_R(29) TF_R(16) TF_R(24)
    x0 += ks2; x1 += k0 + 2u;
    TF_R(13) TF_R(15) TF_R(26) TF_R(6)
    x0 += k0;  x1 += k1 + 3u;
    TF_R(17) TF_R(29) TF_R(16) TF_R(24)
    x0 += k1;  x1 += ks2 + 4u;
    TF_R(13) TF_R(15) TF_R(26) TF_R(6)
    x0 += ks2; x1 += k0 + 5u;
#undef TF_R
    y0 = x0; y1 = x1;
}

// JAX partitionable threefry, x64 off: ctr=(0,j), draw=y0^y1 (certified r4-r18)
__device__ __forceinline__ bool keep_bit(uint32_t j) {
    uint32_t y0, y1;
    threefry_g(0u, 42u, 0u, j, y0, y1);
    return (y0 ^ y1) < 0xE6666600u;
}

// ============ kernel 0: one-time K/V convert (split bf16 + V transpose) ====
__global__ __launch_bounds__(256, 4)
void convert_kv(const float* __restrict__ Kg, const float* __restrict__ Vg,
                short* __restrict__ KH, short* __restrict__ KL,
                short* __restrict__ VT) {
    __shared__ short vs[64][130];
    const int blk = blockIdx.x;           // 512 = 16 b x 32 tiles
    const int b = blk >> 5, t = blk & 31;
    const size_t base = ((size_t)b * S_LEN + (size_t)t * 64) * E_DIM;
    const int e0 = (threadIdx.x & 31) * 4;
    const int rb = threadIdx.x >> 5;
    #pragma unroll
    for (int it = 0; it < 8; ++it) {
        int row = it * 8 + rb;
        f32x4 kv = *(const f32x4*)(Kg + base + row * E_DIM + e0);
        s16x4 h, lo;
        #pragma unroll
        for (int i = 0; i < 4; ++i) {
            short hh = f2bf(kv[i]);
            h[i]  = hh;
            lo[i] = f2bf(kv[i] - bf2f(hh));
        }
        *(s16x4*)(KH + base + row * E_DIM + e0) = h;
        *(s16x4*)(KL + base + row * E_DIM + e0) = lo;
        f32x4 vv = *(const f32x4*)(Vg + base + row * E_DIM + e0);
        #pragma unroll
        for (int i = 0; i < 4; ++i) vs[row][e0 + i] = f2bf(vv[i]);
    }
    __syncthreads();
    const int e = threadIdx.x >> 1;
    const int k2 = (threadIdx.x & 1) * 32;
    short* dst = VT + ((size_t)b * E_DIM + e) * S_LEN + t * 64 + k2;
    #pragma unroll
    for (int i = 0; i < 32; i += 4) {
        s16x4 v;
        #pragma unroll
        for (int q2 = 0; q2 < 4; ++q2) v[q2] = vs[k2 + i + q2][e];
        *(s16x4*)(dst + i) = v;
    }
}

// ===== kernel 1: QT=128, 8-wave swapped-operand flash attn (r15, final) ====
template<int NSPLIT>
__global__ __launch_bounds__(512, 4)
void attn9(const float* __restrict__ Qg, const short* __restrict__ KH,
           const short* __restrict__ KL, const short* __restrict__ VT,
           float* __restrict__ outp) {
    constexpr int NT = (S_LEN / NSPLIT) / KT;
    __shared__ __attribute__((aligned(16))) short kh[KT * E_DIM];  // 8 KB swz
    __shared__ __attribute__((aligned(16))) short kl[KT * E_DIM];  // 8 KB
    __shared__ __attribute__((aligned(16))) short vt[E_DIM * 40];  // 10 KB
    __shared__ __attribute__((aligned(16))) uint32_t plt[8][16 * 20]; // 10 KB
    __shared__ uint32_t mldsT[NT][128];   // NS=4: 8 KB

    const int tid = threadIdx.x;
    const int w   = tid >> 6;             // 0..7
    const int ln  = tid & 63;
    const int r   = ln & 15;
    const int g   = ln >> 4;
    const int nwg = 256 * NSPLIT;
    const int wg  = (blockIdx.x & 7) * (nwg >> 3) + (blockIdx.x >> 3);
    const int t   = wg / NSPLIT;          // 0..255
    const int s   = wg % NSPLIT;
    const int b   = t >> 4;
    const int q0  = (t & 15) << 7;        // 128-row Q tile
    const int k0g = s * (S_LEN / NSPLIT);
    const size_t boff = (size_t)b * S_LEN * E_DIM;

    // ---- Q fragments (B-operand of swapped QK^T), split bf16 in regs ----
    bf16x8 qh[4], ql[4];
    #pragma unroll
    for (int ec = 0; ec < 4; ++ec) {
        const float* src = Qg + boff + (size_t)(q0 + w * 16 + r) * E_DIM + ec * 32 + g * 8;
        f32x4 va = *(const f32x4*)(src);
        f32x4 vb2 = *(const f32x4*)(src + 4);
        #pragma unroll
        for (int i = 0; i < 4; ++i) {
            short hh = f2bf(va[i]);
            qh[ec][i] = hh;
            ql[ec][i] = f2bf(va[i] - bf2f(hh));
            short h2 = f2bf(vb2[i]);
            qh[ec][4 + i] = h2;
            ql[ec][4 + i] = f2bf(vb2[i] - bf2f(h2));
        }
    }

    // ---- mask prologue: wave w covers rows w*16..+15, transposed store ----
    {
        const int segs = (S_LEN / NSPLIT) / 64;
        const uint32_t jb = (((uint32_t)b << 11) + (uint32_t)q0) * 2048u
                          + (uint32_t)k0g + (uint32_t)ln;
        for (int i = 0; i < 16 * segs; ++i) {
            int rr  = w * 16 + i / segs;
            int seg = i % segs;
            uint32_t j = jb + (uint32_t)rr * 2048u + (uint32_t)(seg * 64);
            uint64_t m = __ballot(keep_bit(j));
            if (ln < 2) mldsT[seg * 2 + ln][rr] = (uint32_t)(m >> (ln * 32));
        }
    }

    const short* KHb = KH + ((size_t)b * S_LEN + k0g) * E_DIM;
    const short* KLb = KL + ((size_t)b * S_LEN + k0g) * E_DIM;
    const short* VTb = VT + (size_t)b * E_DIM * S_LEN + k0g;

    // staging (T14): 512 threads stage one 32x128 K tile + 128x32 V^T tile
    bf16x8 skh, skl, svv;
    const int se0 = (tid & 15) * 8;
    const int srl = tid >> 4;             // k-row 0..31
    const int sve = tid >> 2;             // e 0..127
    const int svq = tid & 3;              // chunk 0..3
#define LOAD_TILE(ktt)                                                          \
    {                                                                           \
        skh = *(const bf16x8*)(KHb + (size_t)((ktt) * KT + srl) * E_DIM + se0); \
        skl = *(const bf16x8*)(KLb + (size_t)((ktt) * KT + srl) * E_DIM + se0); \
        svv = *(const bf16x8*)(VTb + (size_t)sve * S_LEN + (ktt) * KT + svq * 8); \
    }
    LOAD_TILE(0)

    f32x4 oacc[8];
    #pragma unroll
    for (int i = 0; i < 8; ++i) oacc[i] = f32x4{0.f, 0.f, 0.f, 0.f};
    float mrun = -1e30f, den = 0.f;

    for (int kt = 0; kt < NT; ++kt) {
        __syncthreads();   // prev tile's LDS readers done (covers mlds at kt=0)
        // ---- LDS writes of staged regs ----
        {
            int idx = (srl * E_DIM + se0) ^ ((srl & 7) << 3);
            *(bf16x8*)(kh + idx) = skh;
            *(bf16x8*)(kl + idx) = skl;
            const int swv = ((sve >> 3) & 1) << 1;
            *(bf16x8*)(vt + sve * 40 + ((svq ^ swv) << 3)) = svv;
        }
        __syncthreads();

        // ---- S^T = K Q^T: 3-MFMA split (certified r10 numerics) ----
        f32x4 sc[2];
        #pragma unroll
        for (int c = 0; c < 2; ++c) {
            f32x4 acc = f32x4{0.f, 0.f, 0.f, 0.f};
            int krow = c * 16 + r;
            int sw = (krow & 7) << 3;
            #pragma unroll
            for (int ec = 0; ec < 4; ++ec) {
                int idx = (krow * E_DIM + ec * 32 + g * 8) ^ sw;
                bf16x8 bh = *(const bf16x8*)(kh + idx);
                bf16x8 bl = *(const bf16x8*)(kl + idx);
                acc = __builtin_amdgcn_mfma_f32_16x16x32_bf16(bh, qh[ec], acc, 0, 0, 0);
                acc = __builtin_amdgcn_mfma_f32_16x16x32_bf16(bl, qh[ec], acc, 0, 0, 0);
                acc = __builtin_amdgcn_mfma_f32_16x16x32_bf16(bh, ql[ec], acc, 0, 0, 0);
            }
            sc[c] = acc;
        }

        // ---- softmax (per-lane scalar state, 2 shuffles per reduce) ----
        float pmax = fmaxf(fmaxf(fmaxf(sc[0][0], sc[0][1]), fmaxf(sc[0][2], sc[0][3])),
                           fmaxf(fmaxf(sc[1][0], sc[1][1]), fmaxf(sc[1][2], sc[1][3])));
        pmax = fmaxf(pmax, __shfl_xor(pmax, 16));
        pmax = fmaxf(pmax, __shfl_xor(pmax, 32));
        if (__any(pmax - mrun > 8.0f)) {       // defer-max
            float mnew = fmaxf(mrun, pmax);
            float scl = __expf(mrun - mnew);
            mrun = mnew;
            den *= scl;
            #pragma unroll
            for (int et = 0; et < 8; ++et) oacc[et] *= scl;
        }
        float rs = 0.f;
        #pragma unroll
        for (int c = 0; c < 2; ++c) {
            #pragma unroll
            for (int reg = 0; reg < 4; ++reg) {
                float p = __expf(sc[c][reg] - mrun);
                sc[c][reg] = p;
                rs += p;
            }
        }
        rs += __shfl_xor(rs, 16);
        rs += __shfl_xor(rs, 32);
        den += rs;

        // ---- issue next tile's global loads (hide under pack + PV) ----
        if (kt + 1 < NT) LOAD_TILE(kt + 1)

        // ---- dropout bits + cvt_pk pack + P^T roundtrip (per-wave LDS) ----
        uint32_t bits = mldsT[kt][w * 16 + r] >> (g * 4);
        float pm[2][4];
        #pragma unroll
        for (int c = 0; c < 2; ++c) {
            #pragma unroll
            for (int reg = 0; reg < 4; ++reg)
                pm[c][reg] = ((bits >> (c * 16 + reg)) & 1u)
                               ? sc[c][reg] * (1.0f / 0.9f) : 0.0f;
        }
        uint2 pk0 = { cvtpk_bf16(pm[0][0], pm[0][1]), cvtpk_bf16(pm[0][2], pm[0][3]) };
        uint2 pk1 = { cvtpk_bf16(pm[1][0], pm[1][1]), cvtpk_bf16(pm[1][2], pm[1][3]) };
        *(uint2*)(&plt[w][r * 20 + g * 2])     = pk0;
        *(uint2*)(&plt[w][r * 20 + 8 + g * 2]) = pk1;
        bf16x8 pfrag = *(const bf16x8*)((const short*)&plt[w][0] + r * 40 + g * 8);

        // ---- O^T += V^T P^T ----
        const int swr = ((r >> 3) & 1) << 1;
        #pragma unroll
        for (int et = 0; et < 8; ++et) {
            const short* vp = vt + (et * 16 + r) * 40 + ((g ^ swr) << 3);
            bf16x8 av = *(const bf16x8*)vp;
            oacc[et] = __builtin_amdgcn_mfma_f32_16x16x32_bf16(av, pfrag, oacc[et], 0, 0, 0);
        }
    }

    // ---- epilogue: O[q=w*16+r][e=et*16+g*4+reg] ----
    const int q = w * 16 + r;             // 0..127
    if (NSPLIT == 1) {
        float inv = 1.0f / den;
        float* dst = outp + boff + (size_t)(q0 + q) * E_DIM;
        #pragma unroll
        for (int et = 0; et < 8; ++et) {
            f32x4 o = oacc[et] * inv;
            *(f32x4*)(dst + et * 16 + g * 4) = o;
        }
    } else {
        float* pb = outp + (size_t)wg * PART2_FLOATS;
        if (g == 0) {
            pb[q]       = mrun;
            pb[128 + q] = den;
        }
        #pragma unroll
        for (int et = 0; et < 8; ++et)
            *(f32x4*)(pb + 256 + q * E_DIM + et * 16 + g * 4) = oacc[et];
    }
}

// ============ kernel 2: merge NSPLIT partials per 128-row tile =============
template<int NSPLIT>
__global__ __launch_bounds__(256, 8)
void merge9(const float* __restrict__ part, float* __restrict__ Og) {
    const int t = blockIdx.x;             // 256 tiles
    const int b = t >> 4;
    const int q0 = (t & 15) << 7;
    const float* ps[NSPLIT];
    #pragma unroll
    for (int s = 0; s < NSPLIT; ++s)
        ps[s] = part + (size_t)(t * NSPLIT + s) * PART2_FLOATS;
    float* dst = Og + (size_t)b * S_LEN * E_DIM + (size_t)q0 * E_DIM;
    for (int i = 0; i < 64; ++i) {
        int idx = i * 256 + threadIdx.x;
        int row = idx >> 7, e = idx & 127;
        float mm = ps[0][row];
        #pragma unroll
        for (int s = 1; s < NSPLIT; ++s) mm = fmaxf(mm, ps[s][row]);
        float d = 0.f, o = 0.f;
        #pragma unroll
        for (int s = 0; s < NSPLIT; ++s) {
            float sc = __expf(ps[s][row] - mm);
            d += ps[s][128 + row] * sc;
            o += ps[s][256 + row * E_DIM + e] * sc;
        }
        dst[row * E_DIM + e] = o / d;
    }
}

// ============ fallback: round-4 mono kernel (certified 409 us) ============
__global__ __launch_bounds__(256, 2)
void attn_mono(const float* __restrict__ Qg, const float* __restrict__ Kg,
               const float* __restrict__ Vg, float* __restrict__ Og) {
    __shared__ short kh[KTM * E_DIM];
    __shared__ short kl[KTM * E_DIM];
    __shared__ short vt[E_DIM * 66];
    __shared__ short pl[4][16 * 64];

    const int tid = threadIdx.x;
    const int w   = tid >> 6;
    const int ln  = tid & 63;
    const int r   = ln & 15;
    const int g   = ln >> 4;
    const int bid = blockIdx.x;
    const int b   = bid >> 5;
    const int q0  = (bid & 31) << 6;
    const size_t boff = (size_t)b * S_LEN * E_DIM;

    {
        const float* src = Qg + boff + (size_t)q0 * E_DIM;
        const int e0 = (tid & 31) * 4;
        const int rb = tid >> 5;
        #pragma unroll
        for (int it = 0; it < 8; ++it) {
            int row = it * 8 + rb;
            f32x4 v = *(const f32x4*)(src + row * E_DIM + e0);
            s16x4 h, lo;
            #pragma unroll
            for (int i = 0; i < 4; ++i) {
                short hh = f2bf(v[i]);
                h[i]  = hh;
                lo[i] = f2bf(v[i] - bf2f(hh));
            }
            int idx = (row * E_DIM + e0) ^ ((row & 7) << 3);
            *(s16x4*)(kh + idx) = h;
            *(s16x4*)(kl + idx) = lo;
        }
    }
    __syncthreads();
    bf16x8 qh[4], ql[4];
    {
        int row = w * 16 + r;
        #pragma unroll
        for (int ec = 0; ec < 4; ++ec) {
            int idx = (row * E_DIM + ec * 32 + g * 8) ^ ((row & 7) << 3);
            qh[ec] = *(const bf16x8*)(kh + idx);
            ql[ec] = *(const bf16x8*)(kl + idx);
        }
    }
    f32x4 oacc[8];
    #pragma unroll
    for (int i = 0; i < 8; ++i) oacc[i] = f32x4{0.f, 0.f, 0.f, 0.f};
    float mrun[4] = {-1e30f, -1e30f, -1e30f, -1e30f};
    float den[4]  = {0.f, 0.f, 0.f, 0.f};

    for (int kt = 0; kt < S_LEN / KTM; ++kt) {
        __syncthreads();
        {
            const float* src = Kg + boff + (size_t)(kt * KTM) * E_DIM;
            const int e0 = (tid & 31) * 4;
            const int rb = tid >> 5;
            #pragma unroll
            for (int it = 0; it < 8; ++it) {
                int row = it * 8 + rb;
                f32x4 v = *(const f32x4*)(src + row * E_DIM + e0);
                s16x4 h, lo;
                #pragma unroll
                for (int i = 0; i < 4; ++i) {
                    short hh = f2bf(v[i]);
                    h[i]  = hh;
                    lo[i] = f2bf(v[i] - bf2f(hh));
                }
                int idx = (row * E_DIM + e0) ^ ((row & 7) << 3);
                *(s16x4*)(kh + idx) = h;
                *(s16x4*)(kl + idx) = lo;
            }
        }
        {
            const float* src = Vg + boff + (size_t)(kt * KTM) * E_DIM;
            const int e0 = (tid & 31) * 4;
            const int kb = (tid >> 5) * 2;
            #pragma unroll
            for (int it = 0; it < 4; ++it) {
                int k = it * 16 + kb;
                f32x4 a  = *(const f32x4*)(src + k * E_DIM + e0);
                f32x4 c2 = *(const f32x4*)(src + (k + 1) * E_DIM + e0);
                #pragma unroll
                for (int ci = 0; ci < 4; ++ci) {
                    uint32_t pack = (uint32_t)(uint16_t)f2bf(a[ci]) |
                                    ((uint32_t)(uint16_t)f2bf(c2[ci]) << 16);
                    *(uint32_t*)(vt + (e0 + ci) * 66 + k) = pack;
                }
            }
        }
        __syncthreads();
        f32x4 sc[4];
        #pragma unroll
        for (int c = 0; c < 4; ++c) {
            f32x4 acc = f32x4{0.f, 0.f, 0.f, 0.f};
            int krow = c * 16 + r;
            int sw = (krow & 7) << 3;
            #pragma unroll
            for (int ec = 0; ec < 4; ++ec) {
                int idx = (krow * E_DIM + ec * 32 + g * 8) ^ sw;
                bf16x8 bh = *(const bf16x8*)(kh + idx);
                bf16x8 bl = *(const bf16x8*)(kl + idx);
                acc = __builtin_amdgcn_mfma_f32_16x16x32_bf16(qh[ec], bh, acc, 0, 0, 0);
                acc = __builtin_amdgcn_mfma_f32_16x16x32_bf16(ql[ec], bh, acc, 0, 0, 0);
                acc = __builtin_amdgcn_mfma_f32_16x16x32_bf16(qh[ec], bl, acc, 0, 0, 0);
            }
            sc[c] = acc;
        }
        float scale[4];
        #pragma unroll
        for (int reg = 0; reg < 4; ++reg) {
            float v0 = fmaxf(fmaxf(sc[0][reg], sc[1][reg]),
                             fmaxf(sc[2][reg], sc[3][reg]));
            v0 = fmaxf(v0, __shfl_xor(v0, 1));
            v0 = fmaxf(v0, __shfl_xor(v0, 2));
            v0 = fmaxf(v0, __shfl_xor(v0, 4));
            v0 = fmaxf(v0, __shfl_xor(v0, 8));
            float mnew = fmaxf(mrun[reg], v0);
            scale[reg] = __expf(mrun[reg] - mnew);
            mrun[reg] = mnew;
        }
        float rs[4] = {0.f, 0.f, 0.f, 0.f};
        #pragma unroll
        for (int c = 0; c < 4; ++c) {
            #pragma unroll
            for (int reg = 0; reg < 4; ++reg) {
                float p = __expf(sc[c][reg] - mrun[reg]);
                sc[c][reg] = p;
                rs[reg] += p;
            }
        }
        #pragma unroll
        for (int reg = 0; reg < 4; ++reg) {
            float v0 = rs[reg];
            v0 += __shfl_xor(v0, 1);
            v0 += __shfl_xor(v0, 2);
            v0 += __shfl_xor(v0, 4);
            v0 += __shfl_xor(v0, 8);
            den[reg] = den[reg] * scale[reg] + v0;
        }
        #pragma unroll
        for (int et = 0; et < 8; ++et) {
            #pragma unroll
            for (int reg = 0; reg < 4; ++reg) oacc[et][reg] *= scale[reg];
        }
        #pragma unroll
        for (int c = 0; c < 4; ++c) {
            int kcol = kt * KTM + c * 16 + r;
            #pragma unroll
            for (int reg = 0; reg < 4; ++reg) {
                int row = g * 4 + reg;
                uint32_t q = (uint32_t)(q0 + w * 16 + row);
                uint32_t j = (((uint32_t)b << 11) + q) * 2048u + (uint32_t)kcol;
                float pm = keep_bit(j) ? sc[c][reg] * (1.0f / 0.9f) : 0.0f;
                int idx = (row * 64 + (c * 16 + r)) ^ ((row & 7) << 3);
                pl[w][idx] = f2bf(pm);
            }
        }
        bf16x8 pa[2];
        #pragma unroll
        for (int st = 0; st < 2; ++st) {
            int idx = (r * 64 + st * 32 + g * 8) ^ ((r & 7) << 3);
            pa[st] = *(const bf16x8*)(&pl[w][0] + idx);
        }
        #pragma unroll
        for (int et = 0; et < 8; ++et) {
            int e = et * 16 + r;
            f32x4 o = oacc[et];
            #pragma unroll
            for (int st = 0; st < 2; ++st) {
                union { bf16x8 v; uint32_t u[4]; } vb;
                #pragma unroll
                for (int i2 = 0; i2 < 4; ++i2)
                    vb.u[i2] = *(const uint32_t*)(vt + e * 66 + st * 32 + g * 8 + i2 * 2);
                o = __builtin_amdgcn_mfma_f32_16x16x32_bf16(pa[st], vb.v, o, 0, 0, 0);
            }
            oacc[et] = o;
        }
    }
    float inv[4];
    #pragma unroll
    for (int reg = 0; reg < 4; ++reg) inv[reg] = 1.0f / den[reg];
    float* dst = Og + boff + (size_t)q0 * E_DIM;
    #pragma unroll
    for (int et = 0; et < 8; ++et) {
        #pragma unroll
        for (int reg = 0; reg < 4; ++reg) {
            int row = w * 16 + g * 4 + reg;
            int e = et * 16 + r;
            dst[row * E_DIM + e] = oacc[et][reg] * inv[reg];
        }
    }
}

extern "C" void kernel_launch(void* const* d_in, const int* in_sizes, int n_in,
                              void* d_out, int out_size, void* d_ws, size_t ws_size,
                              hipStream_t stream) {
    (void)in_sizes; (void)n_in; (void)out_size;
    const float* Q = (const float*)d_in[0];
    const float* K = (const float*)d_in[1];
    const float* V = (const float*)d_in[2];
    float* O = (float*)d_out;
    if (ws_size >= TIER_B) {
        short* KH = (short*)d_ws;
        short* KL = (short*)((char*)d_ws + ARR_BYTES);
        short* VT = (short*)((char*)d_ws + 2u * ARR_BYTES);
        hipLaunchKernelGGL(convert_kv, dim3(512), dim3(256), 0, stream, K, V, KH, KL, VT);
        if (ws_size >= TIER_A4) {
            float* part = (float*)((char*)d_ws + TIER_B);
            hipLaunchKernelGGL((attn9<4>), dim3(1024), dim3(512), 0, stream,
                               Q, KH, KL, VT, part);
            hipLaunchKernelGGL((merge9<4>), dim3(256), dim3(256), 0, stream, part, O);
        } else if (ws_size >= TIER_A2) {
            float* part = (float*)((char*)d_ws + TIER_B);
            hipLaunchKernelGGL((attn9<2>), dim3(512), dim3(512), 0, stream,
                               Q, KH, KL, VT, part);
            hipLaunchKernelGGL((merge9<2>), dim3(256), dim3(256), 0, stream, part, O);
        } else {
            hipLaunchKernelGGL((attn9<1>), dim3(256), dim3(512), 0, stream,
                               Q, KH, KL, VT, O);
        }
    } else {
        hipLaunchKernelGGL(attn_mono, dim3(512), dim3(256), 0, stream, Q, K, V, O);
    }
}